// Round 2
// baseline (7578.120 us; speedup 1.0000x reference)
//
#include <hip/hip_runtime.h>
#include <hip/hip_bf16.h>

// Problem constants (fixed by reference)
#define HIDDEN   64
#define N_USERS  100000
#define N_MOVIES 50000
#define MFEAT    128
#define N_EDGES  2000000
#define N_LABEL  500000

// ---------------------------------------------------------------------------
// Kernel 1: x_movie = movie_x @ lin_W.T + lin_b + movie_emb[movie_node_id]
// One block = 256 threads = 4 waves; each wave handles one movie (lane = h).
// lin_W^T staged in LDS with stride 65 (conflict-free fill + read).
// ---------------------------------------------------------------------------
__global__ __launch_bounds__(256) void k_xmovie(
    const float* __restrict__ movie_x, const int* __restrict__ movie_node_id,
    const float* __restrict__ emb, const float* __restrict__ W,
    const float* __restrict__ b, float* __restrict__ out) {
  __shared__ float Wt[MFEAT * 65];   // Wt[f*65+h] = W[h*128+f]
  __shared__ float row[4][MFEAT];
  int t = threadIdx.x;
  for (int idx = t; idx < HIDDEN * MFEAT; idx += 256) {
    int h = idx >> 7, f = idx & 127;
    Wt[f * 65 + h] = W[idx];
  }
  __syncthreads();
  int slot = t >> 6, h = t & 63;
  int m = blockIdx.x * 4 + slot;           // 50000/4 = 12500 exact
  // stage movie_x row (coalesced: lane h loads f=h and f=h+64)
  row[slot][h]      = movie_x[(size_t)m * MFEAT + h];
  row[slot][h + 64] = movie_x[(size_t)m * MFEAT + 64 + h];
  float acc = b[h] + emb[(size_t)movie_node_id[m] * HIDDEN + h];
#pragma unroll 8
  for (int f = 0; f < MFEAT; ++f) acc += row[slot][f] * Wt[f * 65 + h];
  out[(size_t)m * HIDDEN + h] = acc;
}

// ---------------------------------------------------------------------------
// Kernel 2: x_user[u] = user_emb[user_node_id[u]]   (float4 gather-copy)
// ---------------------------------------------------------------------------
__global__ __launch_bounds__(256) void k_gather_user(
    const float* __restrict__ emb, const int* __restrict__ nid,
    float* __restrict__ out, int n) {
  int gid = blockIdx.x * 256 + threadIdx.x;
  int u = gid >> 4, c = gid & 15;
  if (u >= n) return;
  reinterpret_cast<float4*>(out)[(size_t)u * 16 + c] =
      reinterpret_cast<const float4*>(emb)[(size_t)nid[u] * 16 + c];
}

// ---------------------------------------------------------------------------
// Kernel 3: scatter aggregation. Thread = (edge, quad-of-4-features).
// agg[dst][4q..4q+3] += x_src[src][4q..4q+3]; lane q==0 counts the edge.
// ---------------------------------------------------------------------------
__global__ __launch_bounds__(256) void k_agg(
    const float* __restrict__ xsrc, const int* __restrict__ sidx,
    const int* __restrict__ didx, float* __restrict__ agg,
    int* __restrict__ cnt, int E) {
  int gid = blockIdx.x * 256 + threadIdx.x;
  int e = gid >> 4, q = gid & 15;
  if (e >= E) return;
  int s = sidx[e], d = didx[e];
  float4 v = reinterpret_cast<const float4*>(xsrc + (size_t)s * HIDDEN)[q];
  float* dst = agg + (size_t)d * HIDDEN + q * 4;
  unsafeAtomicAdd(dst + 0, v.x);
  unsafeAtomicAdd(dst + 1, v.y);
  unsafeAtomicAdd(dst + 2, v.z);
  unsafeAtomicAdd(dst + 3, v.w);
  if (cnt && q == 0) atomicAdd(cnt + d, 1);
}

// ---------------------------------------------------------------------------
// Kernel 4: out[node] = relu?( (agg/max(cnt,1)) @ Wl.T + bl + xdst @ Wr.T )
// 4 waves/block, wave per node, lane = output h. Weights transposed in LDS
// (stride 65). Node rows staged in LDS for lane-broadcast reads.
// ---------------------------------------------------------------------------
template <bool RELU>
__global__ __launch_bounds__(256) void k_sage_lin(
    const float* __restrict__ agg, const int* __restrict__ cnt,
    const float* __restrict__ xdst, const float* __restrict__ Wl,
    const float* __restrict__ bl, const float* __restrict__ Wr,
    float* __restrict__ out, int n) {
  __shared__ float WlT[HIDDEN * 65];
  __shared__ float WrT[HIDDEN * 65];
  __shared__ float rowA[4][HIDDEN];
  __shared__ float rowX[4][HIDDEN];
  int t = threadIdx.x;
  for (int idx = t; idx < HIDDEN * HIDDEN; idx += 256) {
    int h = idx >> 6, k = idx & 63;
    WlT[k * 65 + h] = Wl[idx];
    WrT[k * 65 + h] = Wr[idx];
  }
  __syncthreads();
  int slot = t >> 6, h = t & 63;
  int node = blockIdx.x * 4 + slot;        // n divisible by 4 (12500/25000 blocks)
  if (node >= n) return;
  rowA[slot][h] = agg[(size_t)node * HIDDEN + h];
  rowX[slot][h] = xdst[(size_t)node * HIDDEN + h];
  float inv = 1.0f / fmaxf((float)cnt[node], 1.0f);
  float accL = 0.f, accR = 0.f;
#pragma unroll
  for (int k = 0; k < HIDDEN; ++k) {
    accL += rowA[slot][k] * WlT[k * 65 + h];
    accR += rowX[slot][k] * WrT[k * 65 + h];
  }
  float r = inv * accL + bl[h] + accR;
  if (RELU) r = fmaxf(r, 0.f);
  out[(size_t)node * HIDDEN + h] = r;
}

// ---------------------------------------------------------------------------
// Kernel 5: decoder. Wave per label edge; lane h multiplies, shfl-reduce.
// ---------------------------------------------------------------------------
__global__ __launch_bounds__(256) void k_decode(
    const float* __restrict__ ou, const float* __restrict__ om,
    const int* __restrict__ ls, const int* __restrict__ ld,
    float* __restrict__ out, int L) {
  int gid = blockIdx.x * 256 + threadIdx.x;
  int lab = gid >> 6, h = gid & 63;
  if (lab >= L) return;
  float p = ou[(size_t)ls[lab] * HIDDEN + h] * om[(size_t)ld[lab] * HIDDEN + h];
#pragma unroll
  for (int off = 32; off; off >>= 1) p += __shfl_xor(p, off, 64);
  if (h == 0) out[lab] = p;
}

// ---------------------------------------------------------------------------
extern "C" void kernel_launch(void* const* d_in, const int* in_sizes, int n_in,
                              void* d_out, int out_size, void* d_ws, size_t ws_size,
                              hipStream_t stream) {
  // inputs (setup_inputs order)
  const float* movie_x       = (const float*)d_in[0];
  const int*   user_node_id  = (const int*)d_in[1];
  const int*   movie_node_id = (const int*)d_in[2];
  const int*   edge_src_user = (const int*)d_in[3];
  const int*   edge_dst_movie= (const int*)d_in[4];
  const int*   label_src_user= (const int*)d_in[5];
  const int*   label_dst_movie=(const int*)d_in[6];
  const float* user_emb  = (const float*)d_in[7];
  const float* movie_emb = (const float*)d_in[8];
  const float* lin_W     = (const float*)d_in[9];
  const float* lin_b     = (const float*)d_in[10];
  const float* W_l_um1 = (const float*)d_in[11];
  const float* b_l_um1 = (const float*)d_in[12];
  const float* W_r_um1 = (const float*)d_in[13];
  const float* W_l_mu1 = (const float*)d_in[14];
  const float* b_l_mu1 = (const float*)d_in[15];
  const float* W_r_mu1 = (const float*)d_in[16];
  const float* W_l_um2 = (const float*)d_in[17];
  const float* b_l_um2 = (const float*)d_in[18];
  const float* W_r_um2 = (const float*)d_in[19];
  const float* W_l_mu2 = (const float*)d_in[20];
  const float* b_l_mu2 = (const float*)d_in[21];
  const float* W_r_mu2 = (const float*)d_in[22];
  float* out = (float*)d_out;

  // workspace layout (floats)
  float* ws = (float*)d_ws;
  const size_t UH = (size_t)N_USERS * HIDDEN;    // 6.4M
  const size_t MH = (size_t)N_MOVIES * HIDDEN;   // 3.2M
  float* A_user  = ws;                 // x_user  -> later o_user
  float* A_movie = A_user + UH;        // x_movie -> later o_movie
  float* B_user  = A_movie + MH;       // h_user
  float* B_movie = B_user + UH;        // h_movie
  float* AGG     = B_movie + MH;       // shared aggregation buffer (user-sized)
  int*   cnt_user  = (int*)(AGG + UH);
  int*   cnt_movie = cnt_user + N_USERS;

  const int AGG_BLK = (N_EDGES * 16) / 256;          // 125000
  const int DEC_BLK = (N_LABEL * 64) / 256;          // 125000

  // feature init
  k_xmovie<<<N_MOVIES / 4, 256, 0, stream>>>(movie_x, movie_node_id, movie_emb,
                                             lin_W, lin_b, A_movie);
  k_gather_user<<<(N_USERS * 16) / 256, 256, 0, stream>>>(user_emb, user_node_id,
                                                          A_user, N_USERS);

  // ---- layer 1, um: aggregate x_user over edges -> h_movie ----
  hipMemsetAsync(AGG, 0, MH * sizeof(float), stream);
  hipMemsetAsync(cnt_movie, 0, N_MOVIES * sizeof(int), stream);
  k_agg<<<AGG_BLK, 256, 0, stream>>>(A_user, edge_src_user, edge_dst_movie,
                                     AGG, cnt_movie, N_EDGES);
  k_sage_lin<true><<<N_MOVIES / 4, 256, 0, stream>>>(AGG, cnt_movie, A_movie,
                                                     W_l_um1, b_l_um1, W_r_um1,
                                                     B_movie, N_MOVIES);
  // ---- layer 1, mu: aggregate x_movie over edges -> h_user ----
  hipMemsetAsync(AGG, 0, UH * sizeof(float), stream);
  hipMemsetAsync(cnt_user, 0, N_USERS * sizeof(int), stream);
  k_agg<<<AGG_BLK, 256, 0, stream>>>(A_movie, edge_dst_movie, edge_src_user,
                                     AGG, cnt_user, N_EDGES);
  k_sage_lin<true><<<N_USERS / 4, 256, 0, stream>>>(AGG, cnt_user, A_user,
                                                    W_l_mu1, b_l_mu1, W_r_mu1,
                                                    B_user, N_USERS);

  // ---- layer 2, um: aggregate h_user -> o_movie (into A_movie) ----
  hipMemsetAsync(AGG, 0, MH * sizeof(float), stream);
  k_agg<<<AGG_BLK, 256, 0, stream>>>(B_user, edge_src_user, edge_dst_movie,
                                     AGG, nullptr, N_EDGES);
  k_sage_lin<false><<<N_MOVIES / 4, 256, 0, stream>>>(AGG, cnt_movie, B_movie,
                                                      W_l_um2, b_l_um2, W_r_um2,
                                                      A_movie, N_MOVIES);
  // ---- layer 2, mu: aggregate h_movie -> o_user (into A_user) ----
  hipMemsetAsync(AGG, 0, UH * sizeof(float), stream);
  k_agg<<<AGG_BLK, 256, 0, stream>>>(B_movie, edge_dst_movie, edge_src_user,
                                     AGG, nullptr, N_EDGES);
  k_sage_lin<false><<<N_USERS / 4, 256, 0, stream>>>(AGG, cnt_user, B_user,
                                                     W_l_mu2, b_l_mu2, W_r_mu2,
                                                     A_user, N_USERS);

  // ---- decoder ----
  k_decode<<<DEC_BLK, 256, 0, stream>>>(A_user, A_movie, label_src_user,
                                        label_dst_movie, out, N_LABEL);
}

// Round 3
// 1359.785 us; speedup vs baseline: 5.5730x; 5.5730x over previous
//
#include <hip/hip_runtime.h>
#include <hip/hip_bf16.h>

// Problem constants (fixed by reference)
#define HIDDEN   64
#define N_USERS  100000
#define N_MOVIES 50000
#define MFEAT    128
#define N_EDGES  2000000
#define N_LABEL  500000

#define SCAN_ELEMS 1024   // elements scanned per block in phase A (256 thr x 4)

// ---------------------------------------------------------------------------
// Kernel 1: x_movie = movie_x @ lin_W.T + lin_b + movie_emb[movie_node_id]
// 4 waves/block, wave per movie, lane = h. lin_W^T in LDS (stride 65).
// ---------------------------------------------------------------------------
__global__ __launch_bounds__(256) void k_xmovie(
    const float* __restrict__ movie_x, const int* __restrict__ movie_node_id,
    const float* __restrict__ emb, const float* __restrict__ W,
    const float* __restrict__ b, float* __restrict__ out) {
  __shared__ float Wt[MFEAT * 65];   // Wt[f*65+h] = W[h*128+f]
  __shared__ float row[4][MFEAT];
  int t = threadIdx.x;
  for (int idx = t; idx < HIDDEN * MFEAT; idx += 256) {
    int h = idx >> 7, f = idx & 127;
    Wt[f * 65 + h] = W[idx];
  }
  __syncthreads();
  int slot = t >> 6, h = t & 63;
  int m = blockIdx.x * 4 + slot;           // 50000/4 = 12500 exact
  row[slot][h]      = movie_x[(size_t)m * MFEAT + h];
  row[slot][h + 64] = movie_x[(size_t)m * MFEAT + 64 + h];
  float acc = b[h] + emb[(size_t)movie_node_id[m] * HIDDEN + h];
#pragma unroll 8
  for (int f = 0; f < MFEAT; ++f) acc += row[slot][f] * Wt[f * 65 + h];
  out[(size_t)m * HIDDEN + h] = acc;
}

// ---------------------------------------------------------------------------
// Kernel 2: x_user[u] = user_emb[user_node_id[u]]   (float4 gather-copy)
// ---------------------------------------------------------------------------
__global__ __launch_bounds__(256) void k_gather_user(
    const float* __restrict__ emb, const int* __restrict__ nid,
    float* __restrict__ out, int n) {
  int gid = blockIdx.x * 256 + threadIdx.x;
  int u = gid >> 4, c = gid & 15;
  if (u >= n) return;
  reinterpret_cast<float4*>(out)[(size_t)u * 16 + c] =
      reinterpret_cast<const float4*>(emb)[(size_t)nid[u] * 16 + c];
}

// ---------------------------------------------------------------------------
// CSR build: count -> scan (3 phases) -> fill.  Both directions in one pass
// over the edge list; CSRs are reused by both layers.
// ---------------------------------------------------------------------------
__global__ __launch_bounds__(256) void k_count(
    const int* __restrict__ s, const int* __restrict__ d,
    int* __restrict__ cm, int* __restrict__ cu, int E) {
  int e = blockIdx.x * 256 + threadIdx.x;
  if (e >= E) return;
  atomicAdd(cm + d[e], 1);
  atomicAdd(cu + s[e], 1);
}

// Phase A: per-block exclusive scan of 1024 elements + block total.
__global__ __launch_bounds__(256) void k_scan_A(
    const int* __restrict__ cnt, int* __restrict__ rp,
    int* __restrict__ bsum, int n) {
  __shared__ int tsum[256];
  int t = threadIdx.x;
  int base = blockIdx.x * SCAN_ELEMS + t * 4;
  int v0 = base + 0 < n ? cnt[base + 0] : 0;
  int v1 = base + 1 < n ? cnt[base + 1] : 0;
  int v2 = base + 2 < n ? cnt[base + 2] : 0;
  int v3 = base + 3 < n ? cnt[base + 3] : 0;
  int s = v0 + v1 + v2 + v3;
  tsum[t] = s;
  __syncthreads();
  int x = s;
  for (int off = 1; off < 256; off <<= 1) {   // Hillis-Steele inclusive
    int y = (t >= off) ? tsum[t - off] : 0;
    __syncthreads();
    x += y;
    tsum[t] = x;
    __syncthreads();
  }
  int excl = x - s;
  if (base + 0 < n) rp[base + 0] = excl;
  if (base + 1 < n) rp[base + 1] = excl + v0;
  if (base + 2 < n) rp[base + 2] = excl + v0 + v1;
  if (base + 3 < n) rp[base + 3] = excl + v0 + v1 + v2;
  if (t == 255) bsum[blockIdx.x] = x;         // block total
}

// Phase B: single block, exclusive scan of block totals (nb <= 98 < 128).
__global__ __launch_bounds__(128) void k_scan_B(int* bsum, int nb) {
  __shared__ int sh[128];
  int t = threadIdx.x;
  int v = t < nb ? bsum[t] : 0;
  sh[t] = v;
  __syncthreads();
  int x = v;
  for (int off = 1; off < 128; off <<= 1) {
    int y = (t >= off) ? sh[t - off] : 0;
    __syncthreads();
    x += y;
    sh[t] = x;
    __syncthreads();
  }
  if (t < nb) bsum[t] = x - v;                // exclusive
}

// Phase C: add scanned block offsets; write rp[n] = total.
__global__ __launch_bounds__(256) void k_scan_C(
    int* __restrict__ rp, const int* __restrict__ bsum, int n, int total) {
  int i = blockIdx.x * 256 + threadIdx.x;
  if (i < n) rp[i] += bsum[i / SCAN_ELEMS];
  if (i == n) rp[n] = total;
}

__global__ __launch_bounds__(256) void k_fill(
    const int* __restrict__ s, const int* __restrict__ d,
    const int* __restrict__ rpm, const int* __restrict__ rpu,
    int* __restrict__ curm, int* __restrict__ curu,
    int* __restrict__ colm, int* __restrict__ colu, int E) {
  int e = blockIdx.x * 256 + threadIdx.x;
  if (e >= E) return;
  int ss = s[e], dd = d[e];
  int pm = atomicAdd(curm + dd, 1);
  colm[rpm[dd] + pm] = ss;
  int pu = atomicAdd(curu + ss, 1);
  colu[rpu[ss] + pu] = dd;
}

// ---------------------------------------------------------------------------
// Fused SAGE layer: gather-mean over CSR + lin_l + lin_r (+ relu).
// 4 waves/block, wave per dst node, lane = output h. Weights transposed in
// LDS (stride 65, conflict-free). No atomics, no AGG buffer.
// Grid is exact (n % 4 == 0) so every thread reaches __syncthreads().
// ---------------------------------------------------------------------------
template <bool RELU>
__global__ __launch_bounds__(256) void k_sage_fused(
    const float* __restrict__ xsrc, const float* __restrict__ xdst,
    const int* __restrict__ rp, const int* __restrict__ col,
    const float* __restrict__ Wl, const float* __restrict__ bl,
    const float* __restrict__ Wr, float* __restrict__ out, int n) {
  __shared__ float WlT[HIDDEN * 65];
  __shared__ float WrT[HIDDEN * 65];
  __shared__ float rowA[4][HIDDEN];
  __shared__ float rowX[4][HIDDEN];
  int t = threadIdx.x;
  for (int idx = t; idx < HIDDEN * HIDDEN; idx += 256) {
    int h = idx >> 6, k = idx & 63;
    WlT[k * 65 + h] = Wl[idx];
    WrT[k * 65 + h] = Wr[idx];
  }
  int slot = t >> 6, h = t & 63;
  int node = blockIdx.x * 4 + slot;
  int e0 = rp[node], e1 = rp[node + 1];
  float acc = 0.f;
  int e = e0;
  for (; e + 3 < e1; e += 4) {               // 4 independent row-loads in flight
    int s0 = col[e], s1 = col[e + 1], s2 = col[e + 2], s3 = col[e + 3];
    acc += xsrc[(size_t)s0 * HIDDEN + h];
    acc += xsrc[(size_t)s1 * HIDDEN + h];
    acc += xsrc[(size_t)s2 * HIDDEN + h];
    acc += xsrc[(size_t)s3 * HIDDEN + h];
  }
  for (; e < e1; ++e) acc += xsrc[(size_t)col[e] * HIDDEN + h];
  float mean = acc / fmaxf((float)(e1 - e0), 1.0f);
  rowA[slot][h] = mean;
  rowX[slot][h] = xdst[(size_t)node * HIDDEN + h];
  __syncthreads();   // covers weight staging + row staging
  float accL = 0.f, accR = 0.f;
#pragma unroll
  for (int k = 0; k < HIDDEN; ++k) {
    accL += rowA[slot][k] * WlT[k * 65 + h];   // rowA broadcast; WlT 2-way (free)
    accR += rowX[slot][k] * WrT[k * 65 + h];
  }
  float r = accL + bl[h] + accR;
  if (RELU) r = fmaxf(r, 0.f);
  out[(size_t)node * HIDDEN + h] = r;
}

// ---------------------------------------------------------------------------
// Decoder: wave per label edge; lane h multiplies, shfl-reduce.
// ---------------------------------------------------------------------------
__global__ __launch_bounds__(256) void k_decode(
    const float* __restrict__ ou, const float* __restrict__ om,
    const int* __restrict__ ls, const int* __restrict__ ld,
    float* __restrict__ out, int L) {
  int gid = blockIdx.x * 256 + threadIdx.x;
  int lab = gid >> 6, h = gid & 63;
  if (lab >= L) return;
  float p = ou[(size_t)ls[lab] * HIDDEN + h] * om[(size_t)ld[lab] * HIDDEN + h];
#pragma unroll
  for (int off = 32; off; off >>= 1) p += __shfl_xor(p, off, 64);
  if (h == 0) out[lab] = p;
}

// ---------------------------------------------------------------------------
extern "C" void kernel_launch(void* const* d_in, const int* in_sizes, int n_in,
                              void* d_out, int out_size, void* d_ws, size_t ws_size,
                              hipStream_t stream) {
  const float* movie_x        = (const float*)d_in[0];
  const int*   user_node_id   = (const int*)d_in[1];
  const int*   movie_node_id  = (const int*)d_in[2];
  const int*   edge_src_user  = (const int*)d_in[3];
  const int*   edge_dst_movie = (const int*)d_in[4];
  const int*   label_src_user = (const int*)d_in[5];
  const int*   label_dst_movie= (const int*)d_in[6];
  const float* user_emb  = (const float*)d_in[7];
  const float* movie_emb = (const float*)d_in[8];
  const float* lin_W     = (const float*)d_in[9];
  const float* lin_b     = (const float*)d_in[10];
  const float* W_l_um1 = (const float*)d_in[11];
  const float* b_l_um1 = (const float*)d_in[12];
  const float* W_r_um1 = (const float*)d_in[13];
  const float* W_l_mu1 = (const float*)d_in[14];
  const float* b_l_mu1 = (const float*)d_in[15];
  const float* W_r_mu1 = (const float*)d_in[16];
  const float* W_l_um2 = (const float*)d_in[17];
  const float* b_l_um2 = (const float*)d_in[18];
  const float* W_r_um2 = (const float*)d_in[19];
  const float* W_l_mu2 = (const float*)d_in[20];
  const float* b_l_mu2 = (const float*)d_in[21];
  const float* W_r_mu2 = (const float*)d_in[22];
  float* out = (float*)d_out;

  // workspace layout: floats first (16B-aligned), then ints
  float* ws = (float*)d_ws;
  const size_t UH = (size_t)N_USERS * HIDDEN;    // 6.4M floats
  const size_t MH = (size_t)N_MOVIES * HIDDEN;   // 3.2M floats
  float* A_user  = ws;                  // x_user  -> later o_user
  float* A_movie = A_user + UH;         // x_movie -> later o_movie
  float* B_user  = A_movie + MH;        // h_user
  float* B_movie = B_user + UH;         // h_movie
  int* col_m = (int*)(B_movie + MH);    // [N_EDGES] src users per movie
  int* col_u = col_m + N_EDGES;         // [N_EDGES] dst movies per user
  int* rp_m  = col_u + N_EDGES;         // [N_MOVIES+1]
  int* rp_u  = rp_m + (N_MOVIES + 1);   // [N_USERS+1]
  int* cnt_m = rp_u + (N_USERS + 1);    // [N_MOVIES]  counts, then cursors
  int* cnt_u = cnt_m + N_MOVIES;        // [N_USERS]   (contiguous with cnt_m)
  int* bsum  = cnt_u + N_USERS;         // [128] scan block totals (reused)

  const int EB = (N_EDGES + 255) / 256;               // 7813
  const int SA_M = (N_MOVIES + SCAN_ELEMS - 1) / SCAN_ELEMS;   // 49
  const int SA_U = (N_USERS  + SCAN_ELEMS - 1) / SCAN_ELEMS;   // 98

  // feature init
  k_xmovie<<<N_MOVIES / 4, 256, 0, stream>>>(movie_x, movie_node_id, movie_emb,
                                             lin_W, lin_b, A_movie);
  k_gather_user<<<(N_USERS * 16) / 256, 256, 0, stream>>>(user_emb, user_node_id,
                                                          A_user, N_USERS);

  // CSR build (shared by both layers)
  hipMemsetAsync(cnt_m, 0, (N_MOVIES + N_USERS) * sizeof(int), stream);
  k_count<<<EB, 256, 0, stream>>>(edge_src_user, edge_dst_movie, cnt_m, cnt_u, N_EDGES);
  k_scan_A<<<SA_M, 256, 0, stream>>>(cnt_m, rp_m, bsum, N_MOVIES);
  k_scan_B<<<1, 128, 0, stream>>>(bsum, SA_M);
  k_scan_C<<<(N_MOVIES + 256) / 256 + 1, 256, 0, stream>>>(rp_m, bsum, N_MOVIES, N_EDGES);
  k_scan_A<<<SA_U, 256, 0, stream>>>(cnt_u, rp_u, bsum, N_USERS);
  k_scan_B<<<1, 128, 0, stream>>>(bsum, SA_U);
  k_scan_C<<<(N_USERS + 256) / 256 + 1, 256, 0, stream>>>(rp_u, bsum, N_USERS, N_EDGES);
  hipMemsetAsync(cnt_m, 0, (N_MOVIES + N_USERS) * sizeof(int), stream);  // cursors
  k_fill<<<EB, 256, 0, stream>>>(edge_src_user, edge_dst_movie, rp_m, rp_u,
                                 cnt_m, cnt_u, col_m, col_u, N_EDGES);

  // layer 1 (+relu)
  k_sage_fused<true><<<N_MOVIES / 4, 256, 0, stream>>>(
      A_user, A_movie, rp_m, col_m, W_l_um1, b_l_um1, W_r_um1, B_movie, N_MOVIES);
  k_sage_fused<true><<<N_USERS / 4, 256, 0, stream>>>(
      A_movie, A_user, rp_u, col_u, W_l_mu1, b_l_mu1, W_r_mu1, B_user, N_USERS);

  // layer 2 (no activation) — outputs overwrite A_* buffers
  k_sage_fused<false><<<N_MOVIES / 4, 256, 0, stream>>>(
      B_user, B_movie, rp_m, col_m, W_l_um2, b_l_um2, W_r_um2, A_movie, N_MOVIES);
  k_sage_fused<false><<<N_USERS / 4, 256, 0, stream>>>(
      B_movie, B_user, rp_u, col_u, W_l_mu2, b_l_mu2, W_r_mu2, A_user, N_USERS);

  // decoder
  k_decode<<<(N_LABEL * 64) / 256, 256, 0, stream>>>(
      A_user, A_movie, label_src_user, label_dst_movie, out, N_LABEL);
}

// Round 4
// 1209.865 us; speedup vs baseline: 6.2636x; 1.1239x over previous
//
#include <hip/hip_runtime.h>
#include <hip/hip_bf16.h>

// Problem constants (fixed by reference)
#define HIDDEN   64
#define N_USERS  100000
#define N_MOVIES 50000
#define MFEAT    128
#define N_EDGES  2000000
#define N_LABEL  500000

#define SCAN_ELEMS 1024   // elements scanned per block in phase A (256 thr x 4)

// ---------------------------------------------------------------------------
// Kernel 1: x_movie = movie_x @ lin_W.T + lin_b + movie_emb[movie_node_id]
// 4 waves/block, wave per movie, lane = h. lin_W^T in LDS (stride 65).
// ---------------------------------------------------------------------------
__global__ __launch_bounds__(256) void k_xmovie(
    const float* __restrict__ movie_x, const int* __restrict__ movie_node_id,
    const float* __restrict__ emb, const float* __restrict__ W,
    const float* __restrict__ b, float* __restrict__ out) {
  __shared__ float Wt[MFEAT * 65];   // Wt[f*65+h] = W[h*128+f]
  __shared__ float row[4][MFEAT];
  int t = threadIdx.x;
  for (int idx = t; idx < HIDDEN * MFEAT; idx += 256) {
    int h = idx >> 7, f = idx & 127;
    Wt[f * 65 + h] = W[idx];
  }
  __syncthreads();
  int slot = t >> 6, h = t & 63;
  int m = blockIdx.x * 4 + slot;           // 50000/4 = 12500 exact
  row[slot][h]      = movie_x[(size_t)m * MFEAT + h];
  row[slot][h + 64] = movie_x[(size_t)m * MFEAT + 64 + h];
  float acc = b[h] + emb[(size_t)movie_node_id[m] * HIDDEN + h];
#pragma unroll 8
  for (int f = 0; f < MFEAT; ++f) acc += row[slot][f] * Wt[f * 65 + h];
  out[(size_t)m * HIDDEN + h] = acc;
}

// ---------------------------------------------------------------------------
// Kernel 2: x_user[u] = user_emb[user_node_id[u]]   (float4 gather-copy)
// ---------------------------------------------------------------------------
__global__ __launch_bounds__(256) void k_gather_user(
    const float* __restrict__ emb, const int* __restrict__ nid,
    float* __restrict__ out, int n) {
  int gid = blockIdx.x * 256 + threadIdx.x;
  int u = gid >> 4, c = gid & 15;
  if (u >= n) return;
  reinterpret_cast<float4*>(out)[(size_t)u * 16 + c] =
      reinterpret_cast<const float4*>(emb)[(size_t)nid[u] * 16 + c];
}

// ---------------------------------------------------------------------------
// CSR build: count -> scan (3 phases) -> fill (consumes counts as cursors).
// ---------------------------------------------------------------------------
__global__ __launch_bounds__(256) void k_count(
    const int* __restrict__ s, const int* __restrict__ d,
    int* __restrict__ cm, int* __restrict__ cu, int E) {
  int e = blockIdx.x * 256 + threadIdx.x;
  if (e >= E) return;
  atomicAdd(cm + d[e], 1);
  atomicAdd(cu + s[e], 1);
}

// Phase A: per-block exclusive scan of 1024 elements + block total.
__global__ __launch_bounds__(256) void k_scan_A(
    const int* __restrict__ cnt, int* __restrict__ rp,
    int* __restrict__ bsum, int n) {
  __shared__ int tsum[256];
  int t = threadIdx.x;
  int base = blockIdx.x * SCAN_ELEMS + t * 4;
  int v0 = base + 0 < n ? cnt[base + 0] : 0;
  int v1 = base + 1 < n ? cnt[base + 1] : 0;
  int v2 = base + 2 < n ? cnt[base + 2] : 0;
  int v3 = base + 3 < n ? cnt[base + 3] : 0;
  int s = v0 + v1 + v2 + v3;
  tsum[t] = s;
  __syncthreads();
  int x = s;
  for (int off = 1; off < 256; off <<= 1) {   // Hillis-Steele inclusive
    int y = (t >= off) ? tsum[t - off] : 0;
    __syncthreads();
    x += y;
    tsum[t] = x;
    __syncthreads();
  }
  int excl = x - s;
  if (base + 0 < n) rp[base + 0] = excl;
  if (base + 1 < n) rp[base + 1] = excl + v0;
  if (base + 2 < n) rp[base + 2] = excl + v0 + v1;
  if (base + 3 < n) rp[base + 3] = excl + v0 + v1 + v2;
  if (t == 255) bsum[blockIdx.x] = x;         // block total
}

// Phase B: single block, exclusive scan of block totals (nb <= 98 < 128).
__global__ __launch_bounds__(128) void k_scan_B(int* bsum, int nb) {
  __shared__ int sh[128];
  int t = threadIdx.x;
  int v = t < nb ? bsum[t] : 0;
  sh[t] = v;
  __syncthreads();
  int x = v;
  for (int off = 1; off < 128; off <<= 1) {
    int y = (t >= off) ? sh[t - off] : 0;
    __syncthreads();
    x += y;
    sh[t] = x;
    __syncthreads();
  }
  if (t < nb) bsum[t] = x - v;                // exclusive
}

// Phase C: add scanned block offsets; write rp[n] = total.
__global__ __launch_bounds__(256) void k_scan_C(
    int* __restrict__ rp, const int* __restrict__ bsum, int n, int total) {
  int i = blockIdx.x * 256 + threadIdx.x;
  if (i < n) rp[i] += bsum[i / SCAN_ELEMS];
  if (i == n) rp[n] = total;
}

// Fill: cursor = counts, decremented to 0 (order within a node irrelevant).
__global__ __launch_bounds__(256) void k_fill(
    const int* __restrict__ s, const int* __restrict__ d,
    const int* __restrict__ rpm, const int* __restrict__ rpu,
    int* __restrict__ curm, int* __restrict__ curu,
    int* __restrict__ colm, int* __restrict__ colu, int E) {
  int e = blockIdx.x * 256 + threadIdx.x;
  if (e >= E) return;
  int ss = s[e], dd = d[e];
  int pm = atomicAdd(curm + dd, -1) - 1;
  colm[rpm[dd] + pm] = ss;
  int pu = atomicAdd(curu + ss, -1) - 1;
  colu[rpu[ss] + pu] = dd;
}

// ---------------------------------------------------------------------------
// Aggregation: wave per dst node. Lane = (g, q): g = edge subgroup (4 edges
// in flight), q = float4 quad within the 64-float row. No LDS, tiny VGPR ->
// full occupancy. Mean written IN PLACE into the buffer the linear kernel
// will transform. Next-col prefetch overlaps index load with row load.
// ---------------------------------------------------------------------------
__global__ __launch_bounds__(256) void k_agg_mean(
    const float* __restrict__ xsrc, const int* __restrict__ rp,
    const int* __restrict__ col, float* __restrict__ mean_out, int n) {
  int t = threadIdx.x;
  int slot = t >> 6, lane = t & 63;
  int q = lane & 15, g = lane >> 4;
  int node = blockIdx.x * 4 + slot;        // n % 4 == 0
  int e0 = rp[node], e1 = rp[node + 1];
  float4 acc = {0.f, 0.f, 0.f, 0.f};
  int e = e0 + g;
  int s_next = (e < e1) ? col[e] : 0;
  while (e < e1) {
    int s = s_next;
    int en = e + 4;
    if (en < e1) s_next = col[en];         // prefetch next index
    float4 v = reinterpret_cast<const float4*>(xsrc)[(size_t)s * 16 + q];
    acc.x += v.x; acc.y += v.y; acc.z += v.z; acc.w += v.w;
    e = en;
  }
  // reduce the 4 edge subgroups (lanes 16, 32 apart)
  acc.x += __shfl_xor(acc.x, 32, 64); acc.y += __shfl_xor(acc.y, 32, 64);
  acc.z += __shfl_xor(acc.z, 32, 64); acc.w += __shfl_xor(acc.w, 32, 64);
  acc.x += __shfl_xor(acc.x, 16, 64); acc.y += __shfl_xor(acc.y, 16, 64);
  acc.z += __shfl_xor(acc.z, 16, 64); acc.w += __shfl_xor(acc.w, 16, 64);
  if (g == 0) {
    float inv = 1.0f / fmaxf((float)(e1 - e0), 1.0f);
    acc.x *= inv; acc.y *= inv; acc.z *= inv; acc.w *= inv;
    reinterpret_cast<float4*>(mean_out)[(size_t)node * 16 + q] = acc;
  }
}

// ---------------------------------------------------------------------------
// Linear part, IN PLACE: io = relu?( io @ Wl.T + bl + xdst @ Wr.T ).
// 4 waves/block, wave per node, lane = output h. Weights transposed in LDS
// (stride 65, conflict-free both on fill and read).
// ---------------------------------------------------------------------------
template <bool RELU>
__global__ __launch_bounds__(256) void k_sage_lin(
    float* __restrict__ io, const float* __restrict__ xdst,
    const float* __restrict__ Wl, const float* __restrict__ bl,
    const float* __restrict__ Wr, int n) {
  __shared__ float WlT[HIDDEN * 65];
  __shared__ float WrT[HIDDEN * 65];
  __shared__ float rowA[4][HIDDEN];
  __shared__ float rowX[4][HIDDEN];
  int t = threadIdx.x;
  for (int idx = t; idx < HIDDEN * HIDDEN; idx += 256) {
    int h = idx >> 6, k = idx & 63;
    WlT[k * 65 + h] = Wl[idx];
    WrT[k * 65 + h] = Wr[idx];
  }
  int slot = t >> 6, h = t & 63;
  int node = blockIdx.x * 4 + slot;        // n % 4 == 0, grid exact
  rowA[slot][h] = io[(size_t)node * HIDDEN + h];
  rowX[slot][h] = xdst[(size_t)node * HIDDEN + h];
  __syncthreads();   // covers weight staging + row staging
  float accL = 0.f, accR = 0.f;
#pragma unroll
  for (int k = 0; k < HIDDEN; ++k) {
    accL += rowA[slot][k] * WlT[k * 65 + h];
    accR += rowX[slot][k] * WrT[k * 65 + h];
  }
  float r = accL + bl[h] + accR;
  if (RELU) r = fmaxf(r, 0.f);
  io[(size_t)node * HIDDEN + h] = r;
}

// ---------------------------------------------------------------------------
// Decoder: 16 lanes per label edge (float4), 4 labels per wave.
// ---------------------------------------------------------------------------
__global__ __launch_bounds__(256) void k_decode(
    const float* __restrict__ ou, const float* __restrict__ om,
    const int* __restrict__ ls, const int* __restrict__ ld,
    float* __restrict__ out, int L) {
  int gid = blockIdx.x * 256 + threadIdx.x;
  int lab = gid >> 4, q = gid & 15;
  if (lab >= L) return;
  float4 a = reinterpret_cast<const float4*>(ou)[(size_t)ls[lab] * 16 + q];
  float4 b = reinterpret_cast<const float4*>(om)[(size_t)ld[lab] * 16 + q];
  float s = a.x * b.x + a.y * b.y + a.z * b.z + a.w * b.w;
  s += __shfl_xor(s, 1, 64);
  s += __shfl_xor(s, 2, 64);
  s += __shfl_xor(s, 4, 64);
  s += __shfl_xor(s, 8, 64);
  if (q == 0) out[lab] = s;
}

// ---------------------------------------------------------------------------
extern "C" void kernel_launch(void* const* d_in, const int* in_sizes, int n_in,
                              void* d_out, int out_size, void* d_ws, size_t ws_size,
                              hipStream_t stream) {
  const float* movie_x        = (const float*)d_in[0];
  const int*   user_node_id   = (const int*)d_in[1];
  const int*   movie_node_id  = (const int*)d_in[2];
  const int*   edge_src_user  = (const int*)d_in[3];
  const int*   edge_dst_movie = (const int*)d_in[4];
  const int*   label_src_user = (const int*)d_in[5];
  const int*   label_dst_movie= (const int*)d_in[6];
  const float* user_emb  = (const float*)d_in[7];
  const float* movie_emb = (const float*)d_in[8];
  const float* lin_W     = (const float*)d_in[9];
  const float* lin_b     = (const float*)d_in[10];
  const float* W_l_um1 = (const float*)d_in[11];
  const float* b_l_um1 = (const float*)d_in[12];
  const float* W_r_um1 = (const float*)d_in[13];
  const float* W_l_mu1 = (const float*)d_in[14];
  const float* b_l_mu1 = (const float*)d_in[15];
  const float* W_r_mu1 = (const float*)d_in[16];
  const float* W_l_um2 = (const float*)d_in[17];
  const float* b_l_um2 = (const float*)d_in[18];
  const float* W_r_um2 = (const float*)d_in[19];
  const float* W_l_mu2 = (const float*)d_in[20];
  const float* b_l_mu2 = (const float*)d_in[21];
  const float* W_r_mu2 = (const float*)d_in[22];
  float* out = (float*)d_out;

  // workspace layout: floats first (16B-aligned), then ints (~94 MB total)
  float* ws = (float*)d_ws;
  const size_t UH = (size_t)N_USERS * HIDDEN;    // 6.4M floats
  const size_t MH = (size_t)N_MOVIES * HIDDEN;   // 3.2M floats
  float* A_user  = ws;                  // x_user  -> later o_user
  float* A_movie = A_user + UH;         // x_movie -> later o_movie
  float* B_user  = A_movie + MH;        // mean -> h_user (in place)
  float* B_movie = B_user + UH;         // mean -> h_movie (in place)
  int* col_m = (int*)(B_movie + MH);    // [N_EDGES] src users per movie
  int* col_u = col_m + N_EDGES;         // [N_EDGES] dst movies per user
  int* rp_m  = col_u + N_EDGES;         // [N_MOVIES+1]
  int* rp_u  = rp_m + (N_MOVIES + 1);   // [N_USERS+1]
  int* cnt_m = rp_u + (N_USERS + 1);    // [N_MOVIES]  counts -> fill cursors
  int* cnt_u = cnt_m + N_MOVIES;        // [N_USERS]   (contiguous with cnt_m)
  int* bsum  = cnt_u + N_USERS;         // [128] scan block totals (reused)

  const int EB = (N_EDGES + 255) / 256;                        // 7813
  const int SA_M = (N_MOVIES + SCAN_ELEMS - 1) / SCAN_ELEMS;   // 49
  const int SA_U = (N_USERS  + SCAN_ELEMS - 1) / SCAN_ELEMS;   // 98

  // feature init
  k_xmovie<<<N_MOVIES / 4, 256, 0, stream>>>(movie_x, movie_node_id, movie_emb,
                                             lin_W, lin_b, A_movie);
  k_gather_user<<<(N_USERS * 16) / 256, 256, 0, stream>>>(user_emb, user_node_id,
                                                          A_user, N_USERS);

  // CSR build (shared by both layers)
  hipMemsetAsync(cnt_m, 0, (N_MOVIES + N_USERS) * sizeof(int), stream);
  k_count<<<EB, 256, 0, stream>>>(edge_src_user, edge_dst_movie, cnt_m, cnt_u, N_EDGES);
  k_scan_A<<<SA_M, 256, 0, stream>>>(cnt_m, rp_m, bsum, N_MOVIES);
  k_scan_B<<<1, 128, 0, stream>>>(bsum, SA_M);
  k_scan_C<<<(N_MOVIES + 256) / 256 + 1, 256, 0, stream>>>(rp_m, bsum, N_MOVIES, N_EDGES);
  k_scan_A<<<SA_U, 256, 0, stream>>>(cnt_u, rp_u, bsum, N_USERS);
  k_scan_B<<<1, 128, 0, stream>>>(bsum, SA_U);
  k_scan_C<<<(N_USERS + 256) / 256 + 1, 256, 0, stream>>>(rp_u, bsum, N_USERS, N_EDGES);
  k_fill<<<EB, 256, 0, stream>>>(edge_src_user, edge_dst_movie, rp_m, rp_u,
                                 cnt_m, cnt_u, col_m, col_u, N_EDGES);

  // layer 1 (+relu): mean into B_*, then in-place linear
  k_agg_mean<<<N_MOVIES / 4, 256, 0, stream>>>(A_user, rp_m, col_m, B_movie, N_MOVIES);
  k_sage_lin<true><<<N_MOVIES / 4, 256, 0, stream>>>(B_movie, A_movie,
                                                     W_l_um1, b_l_um1, W_r_um1, N_MOVIES);
  k_agg_mean<<<N_USERS / 4, 256, 0, stream>>>(A_movie, rp_u, col_u, B_user, N_USERS);
  k_sage_lin<true><<<N_USERS / 4, 256, 0, stream>>>(B_user, A_user,
                                                    W_l_mu1, b_l_mu1, W_r_mu1, N_USERS);

  // layer 2 (no activation): mean into A_* (x_* dead), in-place linear
  k_agg_mean<<<N_MOVIES / 4, 256, 0, stream>>>(B_user, rp_m, col_m, A_movie, N_MOVIES);
  k_sage_lin<false><<<N_MOVIES / 4, 256, 0, stream>>>(A_movie, B_movie,
                                                      W_l_um2, b_l_um2, W_r_um2, N_MOVIES);
  k_agg_mean<<<N_USERS / 4, 256, 0, stream>>>(B_movie, rp_u, col_u, A_user, N_USERS);
  k_sage_lin<false><<<N_USERS / 4, 256, 0, stream>>>(A_user, B_user,
                                                     W_l_mu2, b_l_mu2, W_r_mu2, N_USERS);

  // decoder
  k_decode<<<(N_LABEL * 16) / 256, 256, 0, stream>>>(
      A_user, A_movie, label_src_user, label_dst_movie, out, N_LABEL);
}

// Round 6
// 1157.180 us; speedup vs baseline: 6.5488x; 1.0455x over previous
//
#include <hip/hip_runtime.h>
#include <hip/hip_bf16.h>

// Problem constants (fixed by reference)
#define HIDDEN   64
#define N_USERS  100000
#define N_MOVIES 50000
#define MFEAT    128
#define N_EDGES  2000000
#define N_LABEL  500000

#define SCAN_ELEMS 1024   // elements scanned per block in phase A (256 thr x 4)

// bf16 helpers (RNE; inputs finite)
__device__ __forceinline__ float bf2f(unsigned short u) {
  union { unsigned int i; float f; } c; c.i = ((unsigned int)u) << 16; return c.f;
}
__device__ __forceinline__ unsigned short f2bf(float x) {
  union { float f; unsigned int i; } c; c.f = x;
  unsigned int r = c.i + 0x7FFFu + ((c.i >> 16) & 1u);
  return (unsigned short)(r >> 16);
}

// ---------------------------------------------------------------------------
// Kernel 1: x_movie = movie_x @ lin_W.T + lin_b + movie_emb[movie_node_id]
// 4 waves/block, wave per movie, lane = h. lin_W^T in LDS (stride 65).
// Also writes bf16 shadow (aggregation gather source).
// ---------------------------------------------------------------------------
__global__ __launch_bounds__(256) void k_xmovie(
    const float* __restrict__ movie_x, const int* __restrict__ movie_node_id,
    const float* __restrict__ emb, const float* __restrict__ W,
    const float* __restrict__ b, float* __restrict__ out,
    unsigned short* __restrict__ sh) {
  __shared__ float Wt[MFEAT * 65];   // Wt[f*65+h] = W[h*128+f]
  __shared__ float row[4][MFEAT];
  int t = threadIdx.x;
  for (int idx = t; idx < HIDDEN * MFEAT; idx += 256) {
    int h = idx >> 7, f = idx & 127;
    Wt[f * 65 + h] = W[idx];
  }
  __syncthreads();
  int slot = t >> 6, h = t & 63;
  int m = blockIdx.x * 4 + slot;           // 50000/4 = 12500 exact
  row[slot][h]      = movie_x[(size_t)m * MFEAT + h];
  row[slot][h + 64] = movie_x[(size_t)m * MFEAT + 64 + h];
  float acc = b[h] + emb[(size_t)movie_node_id[m] * HIDDEN + h];
#pragma unroll 8
  for (int f = 0; f < MFEAT; ++f) acc += row[slot][f] * Wt[f * 65 + h];
  out[(size_t)m * HIDDEN + h] = acc;
  sh[(size_t)m * HIDDEN + h] = f2bf(acc);
}

// ---------------------------------------------------------------------------
// Kernel 2: x_user[u] = user_emb[user_node_id[u]]  (float4 gather-copy)
// + bf16 shadow.
// ---------------------------------------------------------------------------
__global__ __launch_bounds__(256) void k_gather_user(
    const float* __restrict__ emb, const int* __restrict__ nid,
    float* __restrict__ out, unsigned short* __restrict__ sh, int n) {
  int gid = blockIdx.x * 256 + threadIdx.x;
  int u = gid >> 4, c = gid & 15;
  if (u >= n) return;
  float4 v = reinterpret_cast<const float4*>(emb)[(size_t)nid[u] * 16 + c];
  reinterpret_cast<float4*>(out)[(size_t)u * 16 + c] = v;
  ushort4 s4;
  s4.x = f2bf(v.x); s4.y = f2bf(v.y); s4.z = f2bf(v.z); s4.w = f2bf(v.w);
  reinterpret_cast<ushort4*>(sh)[(size_t)u * 16 + c] = s4;
}

// ---------------------------------------------------------------------------
// CSR build: count -> scan (3 phases) -> fill (consumes counts as cursors).
// count/fill process 4 edges/thread (int4 loads) for memory-level parallelism.
// ---------------------------------------------------------------------------
__global__ __launch_bounds__(256) void k_count(
    const int* __restrict__ s, const int* __restrict__ d,
    int* __restrict__ cm, int* __restrict__ cu, int E) {
  int base = (blockIdx.x * 256 + threadIdx.x) * 4;
  if (base >= E) return;
  int4 ss = *reinterpret_cast<const int4*>(s + base);
  int4 dd = *reinterpret_cast<const int4*>(d + base);
  atomicAdd(cm + dd.x, 1); atomicAdd(cm + dd.y, 1);
  atomicAdd(cm + dd.z, 1); atomicAdd(cm + dd.w, 1);
  atomicAdd(cu + ss.x, 1); atomicAdd(cu + ss.y, 1);
  atomicAdd(cu + ss.z, 1); atomicAdd(cu + ss.w, 1);
}

// Phase A: per-block exclusive scan of 1024 elements + block total.
__global__ __launch_bounds__(256) void k_scan_A(
    const int* __restrict__ cnt, int* __restrict__ rp,
    int* __restrict__ bsum, int n) {
  __shared__ int tsum[256];
  int t = threadIdx.x;
  int base = blockIdx.x * SCAN_ELEMS + t * 4;
  int v0 = base + 0 < n ? cnt[base + 0] : 0;
  int v1 = base + 1 < n ? cnt[base + 1] : 0;
  int v2 = base + 2 < n ? cnt[base + 2] : 0;
  int v3 = base + 3 < n ? cnt[base + 3] : 0;
  int s = v0 + v1 + v2 + v3;
  tsum[t] = s;
  __syncthreads();
  int x = s;
  for (int off = 1; off < 256; off <<= 1) {   // Hillis-Steele inclusive
    int y = (t >= off) ? tsum[t - off] : 0;
    __syncthreads();
    x += y;
    tsum[t] = x;
    __syncthreads();
  }
  int excl = x - s;
  if (base + 0 < n) rp[base + 0] = excl;
  if (base + 1 < n) rp[base + 1] = excl + v0;
  if (base + 2 < n) rp[base + 2] = excl + v0 + v1;
  if (base + 3 < n) rp[base + 3] = excl + v0 + v1 + v2;
  if (t == 255) bsum[blockIdx.x] = x;         // block total
}

// Phase B: single block, exclusive scan of block totals (nb <= 98 < 128).
__global__ __launch_bounds__(128) void k_scan_B(int* bsum, int nb) {
  __shared__ int sh[128];
  int t = threadIdx.x;
  int v = t < nb ? bsum[t] : 0;
  sh[t] = v;
  __syncthreads();
  int x = v;
  for (int off = 1; off < 128; off <<= 1) {
    int y = (t >= off) ? sh[t - off] : 0;
    __syncthreads();
    x += y;
    sh[t] = x;
    __syncthreads();
  }
  if (t < nb) bsum[t] = x - v;                // exclusive
}

// Phase C: add scanned block offsets; write rp[n] = total.
__global__ __launch_bounds__(256) void k_scan_C(
    int* __restrict__ rp, const int* __restrict__ bsum, int n, int total) {
  int i = blockIdx.x * 256 + threadIdx.x;
  if (i < n) rp[i] += bsum[i / SCAN_ELEMS];
  if (i == n) rp[n] = total;
}

// Fill: cursors = counts, decremented to 0 (order within a node irrelevant).
// col_u entries are movie ids (< 65536) -> uint16.
__global__ __launch_bounds__(256) void k_fill(
    const int* __restrict__ s, const int* __restrict__ d,
    const int* __restrict__ rpm, const int* __restrict__ rpu,
    int* __restrict__ curm, int* __restrict__ curu,
    int* __restrict__ colm, unsigned short* __restrict__ colu, int E) {
  int base = (blockIdx.x * 256 + threadIdx.x) * 4;
  if (base >= E) return;
  int4 ss = *reinterpret_cast<const int4*>(s + base);
  int4 dd = *reinterpret_cast<const int4*>(d + base);
  int rm0 = rpm[dd.x], rm1 = rpm[dd.y], rm2 = rpm[dd.z], rm3 = rpm[dd.w];
  int ru0 = rpu[ss.x], ru1 = rpu[ss.y], ru2 = rpu[ss.z], ru3 = rpu[ss.w];
  int pm0 = atomicAdd(curm + dd.x, -1) - 1;
  int pm1 = atomicAdd(curm + dd.y, -1) - 1;
  int pm2 = atomicAdd(curm + dd.z, -1) - 1;
  int pm3 = atomicAdd(curm + dd.w, -1) - 1;
  int pu0 = atomicAdd(curu + ss.x, -1) - 1;
  int pu1 = atomicAdd(curu + ss.y, -1) - 1;
  int pu2 = atomicAdd(curu + ss.z, -1) - 1;
  int pu3 = atomicAdd(curu + ss.w, -1) - 1;
  colm[rm0 + pm0] = ss.x;
  colm[rm1 + pm1] = ss.y;
  colm[rm2 + pm2] = ss.z;
  colm[rm3 + pm3] = ss.w;
  colu[ru0 + pu0] = (unsigned short)dd.x;
  colu[ru1 + pu1] = (unsigned short)dd.y;
  colu[ru2 + pu2] = (unsigned short)dd.z;
  colu[ru3 + pu3] = (unsigned short)dd.w;
}

// ---------------------------------------------------------------------------
// Aggregation from bf16 shadow: wave per dst node. Lane = (g, q): g = edge
// subgroup (4 edges in flight), q = ushort4 quad (4 feats). Row = 128B across
// 16 lanes. No LDS, tiny VGPR -> full occupancy. Mean written (f32) in place
// into the buffer the linear kernel transforms.
// ---------------------------------------------------------------------------
template <typename IdxT>
__global__ __launch_bounds__(256) void k_agg_mean(
    const unsigned short* __restrict__ xsrc_bf, const int* __restrict__ rp,
    const IdxT* __restrict__ col, float* __restrict__ mean_out, int n) {
  int t = threadIdx.x;
  int slot = t >> 6, lane = t & 63;
  int q = lane & 15, g = lane >> 4;
  int node = blockIdx.x * 4 + slot;        // n % 4 == 0
  int e0 = rp[node], e1 = rp[node + 1];
  float4 acc = {0.f, 0.f, 0.f, 0.f};
  int e = e0 + g;
  int s_next = (e < e1) ? (int)col[e] : 0;
  while (e < e1) {
    int s = s_next;
    int en = e + 4;
    if (en < e1) s_next = (int)col[en];    // prefetch next index
    ushort4 v = reinterpret_cast<const ushort4*>(xsrc_bf)[(size_t)s * 16 + q];
    acc.x += bf2f(v.x); acc.y += bf2f(v.y);
    acc.z += bf2f(v.z); acc.w += bf2f(v.w);
    e = en;
  }
  // reduce the 4 edge subgroups (lanes 16, 32 apart)
  acc.x += __shfl_xor(acc.x, 32, 64); acc.y += __shfl_xor(acc.y, 32, 64);
  acc.z += __shfl_xor(acc.z, 32, 64); acc.w += __shfl_xor(acc.w, 32, 64);
  acc.x += __shfl_xor(acc.x, 16, 64); acc.y += __shfl_xor(acc.y, 16, 64);
  acc.z += __shfl_xor(acc.z, 16, 64); acc.w += __shfl_xor(acc.w, 16, 64);
  if (g == 0) {
    float inv = 1.0f / fmaxf((float)(e1 - e0), 1.0f);
    acc.x *= inv; acc.y *= inv; acc.z *= inv; acc.w *= inv;
    reinterpret_cast<float4*>(mean_out)[(size_t)node * 16 + q] = acc;
  }
}

// ---------------------------------------------------------------------------
// Linear part, IN PLACE: io = relu?( io @ Wl.T + bl + xdst @ Wr.T ).
// Optionally writes a bf16 shadow (for the next layer's gather).
// ---------------------------------------------------------------------------
template <bool RELU>
__global__ __launch_bounds__(256) void k_sage_lin(
    float* __restrict__ io, const float* __restrict__ xdst,
    const float* __restrict__ Wl, const float* __restrict__ bl,
    const float* __restrict__ Wr, unsigned short* __restrict__ sh_out, int n) {
  __shared__ float WlT[HIDDEN * 65];
  __shared__ float WrT[HIDDEN * 65];
  __shared__ float rowA[4][HIDDEN];
  __shared__ float rowX[4][HIDDEN];
  int t = threadIdx.x;
  for (int idx = t; idx < HIDDEN * HIDDEN; idx += 256) {
    int h = idx >> 6, k = idx & 63;
    WlT[k * 65 + h] = Wl[idx];
    WrT[k * 65 + h] = Wr[idx];
  }
  int slot = t >> 6, h = t & 63;
  int node = blockIdx.x * 4 + slot;        // n % 4 == 0, grid exact
  rowA[slot][h] = io[(size_t)node * HIDDEN + h];
  rowX[slot][h] = xdst[(size_t)node * HIDDEN + h];
  __syncthreads();   // covers weight staging + row staging
  float accL = 0.f, accR = 0.f;
#pragma unroll
  for (int k = 0; k < HIDDEN; ++k) {
    accL += rowA[slot][k] * WlT[k * 65 + h];
    accR += rowX[slot][k] * WrT[k * 65 + h];
  }
  float r = accL + bl[h] + accR;
  if (RELU) r = fmaxf(r, 0.f);
  io[(size_t)node * HIDDEN + h] = r;
  if (sh_out) sh_out[(size_t)node * HIDDEN + h] = f2bf(r);
}

// ---------------------------------------------------------------------------
// Decoder: 16 lanes per label edge (float4), 4 labels per wave. f32 tables.
// ---------------------------------------------------------------------------
__global__ __launch_bounds__(256) void k_decode(
    const float* __restrict__ ou, const float* __restrict__ om,
    const int* __restrict__ ls, const int* __restrict__ ld,
    float* __restrict__ out, int L) {
  int gid = blockIdx.x * 256 + threadIdx.x;
  int lab = gid >> 4, q = gid & 15;
  if (lab >= L) return;
  float4 a = reinterpret_cast<const float4*>(ou)[(size_t)ls[lab] * 16 + q];
  float4 b = reinterpret_cast<const float4*>(om)[(size_t)ld[lab] * 16 + q];
  float s = a.x * b.x + a.y * b.y + a.z * b.z + a.w * b.w;
  s += __shfl_xor(s, 1, 64);
  s += __shfl_xor(s, 2, 64);
  s += __shfl_xor(s, 4, 64);
  s += __shfl_xor(s, 8, 64);
  if (q == 0) out[lab] = s;
}

// ---------------------------------------------------------------------------
extern "C" void kernel_launch(void* const* d_in, const int* in_sizes, int n_in,
                              void* d_out, int out_size, void* d_ws, size_t ws_size,
                              hipStream_t stream) {
  const float* movie_x        = (const float*)d_in[0];
  const int*   user_node_id   = (const int*)d_in[1];
  const int*   movie_node_id  = (const int*)d_in[2];
  const int*   edge_src_user  = (const int*)d_in[3];
  const int*   edge_dst_movie = (const int*)d_in[4];
  const int*   label_src_user = (const int*)d_in[5];
  const int*   label_dst_movie= (const int*)d_in[6];
  const float* user_emb  = (const float*)d_in[7];
  const float* movie_emb = (const float*)d_in[8];
  const float* lin_W     = (const float*)d_in[9];
  const float* lin_b     = (const float*)d_in[10];
  const float* W_l_um1 = (const float*)d_in[11];
  const float* b_l_um1 = (const float*)d_in[12];
  const float* W_r_um1 = (const float*)d_in[13];
  const float* W_l_mu1 = (const float*)d_in[14];
  const float* b_l_mu1 = (const float*)d_in[15];
  const float* W_r_mu1 = (const float*)d_in[16];
  const float* W_l_um2 = (const float*)d_in[17];
  const float* b_l_um2 = (const float*)d_in[18];
  const float* W_r_um2 = (const float*)d_in[19];
  const float* W_l_mu2 = (const float*)d_in[20];
  const float* b_l_mu2 = (const float*)d_in[21];
  const float* W_r_mu2 = (const float*)d_in[22];
  float* out = (float*)d_out;

  // workspace layout: f32 tables, bf16 shadows, then ints  (~116 MB)
  float* ws = (float*)d_ws;
  const size_t UH = (size_t)N_USERS * HIDDEN;    // 6.4M elems
  const size_t MH = (size_t)N_MOVIES * HIDDEN;   // 3.2M elems
  float* A_user  = ws;                  // x_user  -> later o_user
  float* A_movie = A_user + UH;         // x_movie -> later o_movie
  float* B_user  = A_movie + MH;        // mean -> h_user (in place)
  float* B_movie = B_user + UH;         // mean -> h_movie (in place)
  unsigned short* xu_sh = (unsigned short*)(B_movie + MH);  // [UH] also hu_sh
  unsigned short* xm_sh = xu_sh + UH;   // [MH]
  unsigned short* hm_sh = xm_sh + MH;   // [MH]
  unsigned short* hu_sh = xu_sh;        // reuse (xu_sh dead after agg1-movie)
  int* col_m = (int*)(hm_sh + MH);      // [N_EDGES] src users per movie
  unsigned short* col_u = (unsigned short*)(col_m + N_EDGES); // [N_EDGES]
  int* rp_m  = (int*)(col_u + N_EDGES); // [N_MOVIES+1]
  int* rp_u  = rp_m + (N_MOVIES + 1);   // [N_USERS+1]
  int* cnt_m = rp_u + (N_USERS + 1);    // [N_MOVIES]  counts -> fill cursors
  int* cnt_u = cnt_m + N_MOVIES;        // [N_USERS]   (contiguous with cnt_m)
  int* bsum  = cnt_u + N_USERS;         // [128] scan block totals (reused)

  const int E4B = (N_EDGES / 4 + 255) / 256;                   // 1954
  const int SA_M = (N_MOVIES + SCAN_ELEMS - 1) / SCAN_ELEMS;   // 49
  const int SA_U = (N_USERS  + SCAN_ELEMS - 1) / SCAN_ELEMS;   // 98

  // feature init (+ bf16 shadows)
  k_xmovie<<<N_MOVIES / 4, 256, 0, stream>>>(movie_x, movie_node_id, movie_emb,
                                             lin_W, lin_b, A_movie, xm_sh);
  k_gather_user<<<(N_USERS * 16) / 256, 256, 0, stream>>>(user_emb, user_node_id,
                                                          A_user, xu_sh, N_USERS);

  // CSR build (shared by both layers)
  hipMemsetAsync(cnt_m, 0, (N_MOVIES + N_USERS) * sizeof(int), stream);
  k_count<<<E4B, 256, 0, stream>>>(edge_src_user, edge_dst_movie, cnt_m, cnt_u, N_EDGES);
  k_scan_A<<<SA_M, 256, 0, stream>>>(cnt_m, rp_m, bsum, N_MOVIES);
  k_scan_B<<<1, 128, 0, stream>>>(bsum, SA_M);
  k_scan_C<<<(N_MOVIES + 256) / 256 + 1, 256, 0, stream>>>(rp_m, bsum, N_MOVIES, N_EDGES);
  k_scan_A<<<SA_U, 256, 0, stream>>>(cnt_u, rp_u, bsum, N_USERS);
  k_scan_B<<<1, 128, 0, stream>>>(bsum, SA_U);
  k_scan_C<<<(N_USERS + 256) / 256 + 1, 256, 0, stream>>>(rp_u, bsum, N_USERS, N_EDGES);
  k_fill<<<E4B, 256, 0, stream>>>(edge_src_user, edge_dst_movie, rp_m, rp_u,
                                  cnt_m, cnt_u, col_m, col_u, N_EDGES);

  // layer 1 (+relu): mean into B_*, in-place linear (h shadows out)
  k_agg_mean<int><<<N_MOVIES / 4, 256, 0, stream>>>(xu_sh, rp_m, col_m, B_movie, N_MOVIES);
  k_sage_lin<true><<<N_MOVIES / 4, 256, 0, stream>>>(B_movie, A_movie,
                                                     W_l_um1, b_l_um1, W_r_um1, hm_sh, N_MOVIES);
  k_agg_mean<unsigned short><<<N_USERS / 4, 256, 0, stream>>>(xm_sh, rp_u, col_u, B_user, N_USERS);
  k_sage_lin<true><<<N_USERS / 4, 256, 0, stream>>>(B_user, A_user,
                                                    W_l_mu1, b_l_mu1, W_r_mu1, hu_sh, N_USERS);

  // layer 2 (no activation): mean into A_* (x_* dead), in-place linear
  k_agg_mean<int><<<N_MOVIES / 4, 256, 0, stream>>>(hu_sh, rp_m, col_m, A_movie, N_MOVIES);
  k_sage_lin<false><<<N_MOVIES / 4, 256, 0, stream>>>(A_movie, B_movie,
                                                      W_l_um2, b_l_um2, W_r_um2, nullptr, N_MOVIES);
  k_agg_mean<unsigned short><<<N_USERS / 4, 256, 0, stream>>>(hm_sh, rp_u, col_u, A_user, N_USERS);
  k_sage_lin<false><<<N_USERS / 4, 256, 0, stream>>>(A_user, B_user,
                                                     W_l_mu2, b_l_mu2, W_r_mu2, nullptr, N_USERS);

  // decoder (f32 tables)
  k_decode<<<(N_LABEL * 16) / 256, 256, 0, stream>>>(
      A_user, A_movie, label_src_user, label_dst_movie, out, N_LABEL);
}

// Round 7
// 828.824 us; speedup vs baseline: 9.1432x; 1.3962x over previous
//
#include <hip/hip_runtime.h>
#include <hip/hip_bf16.h>

// Problem constants (fixed by reference)
#define HIDDEN   64
#define N_USERS  100000
#define N_MOVIES 50000
#define MFEAT    128
#define N_EDGES  2000000
#define N_LABEL  500000

#define NB_M 196     // ceil(50000/256)  coarse buckets by movie id >> 8
#define NB_U 391     // ceil(100000/256) coarse buckets by user id >> 8
#define PCHUNK 4096  // edges per partition block (512 thr x 8)

// bf16 helpers (RNE; inputs finite)
__device__ __forceinline__ float bf2f(unsigned short u) {
  union { unsigned int i; float f; } c; c.i = ((unsigned int)u) << 16; return c.f;
}
__device__ __forceinline__ unsigned short f2bf(float x) {
  union { float f; unsigned int i; } c; c.f = x;
  unsigned int r = c.i + 0x7FFFu + ((c.i >> 16) & 1u);
  return (unsigned short)(r >> 16);
}

// ---------------------------------------------------------------------------
// Kernel 1: x_movie = movie_x @ lin_W.T + lin_b + movie_emb[movie_node_id]
// 4 waves/block, wave per movie, lane = h. lin_W^T in LDS (stride 65).
// Also writes bf16 shadow (aggregation gather source).
// ---------------------------------------------------------------------------
__global__ __launch_bounds__(256) void k_xmovie(
    const float* __restrict__ movie_x, const int* __restrict__ movie_node_id,
    const float* __restrict__ emb, const float* __restrict__ W,
    const float* __restrict__ b, float* __restrict__ out,
    unsigned short* __restrict__ sh) {
  __shared__ float Wt[MFEAT * 65];   // Wt[f*65+h] = W[h*128+f]
  __shared__ float row[4][MFEAT];
  int t = threadIdx.x;
  for (int idx = t; idx < HIDDEN * MFEAT; idx += 256) {
    int h = idx >> 7, f = idx & 127;
    Wt[f * 65 + h] = W[idx];
  }
  __syncthreads();
  int slot = t >> 6, h = t & 63;
  int m = blockIdx.x * 4 + slot;           // 50000/4 = 12500 exact
  row[slot][h]      = movie_x[(size_t)m * MFEAT + h];
  row[slot][h + 64] = movie_x[(size_t)m * MFEAT + 64 + h];
  float acc = b[h] + emb[(size_t)movie_node_id[m] * HIDDEN + h];
#pragma unroll 8
  for (int f = 0; f < MFEAT; ++f) acc += row[slot][f] * Wt[f * 65 + h];
  out[(size_t)m * HIDDEN + h] = acc;
  sh[(size_t)m * HIDDEN + h] = f2bf(acc);
}

// ---------------------------------------------------------------------------
// Kernel 2: x_user[u] = user_emb[user_node_id[u]]  (float4 gather-copy)
// + bf16 shadow.
// ---------------------------------------------------------------------------
__global__ __launch_bounds__(256) void k_gather_user(
    const float* __restrict__ emb, const int* __restrict__ nid,
    float* __restrict__ out, unsigned short* __restrict__ sh, int n) {
  int gid = blockIdx.x * 256 + threadIdx.x;
  int u = gid >> 4, c = gid & 15;
  if (u >= n) return;
  float4 v = reinterpret_cast<const float4*>(emb)[(size_t)nid[u] * 16 + c];
  reinterpret_cast<float4*>(out)[(size_t)u * 16 + c] = v;
  ushort4 s4;
  s4.x = f2bf(v.x); s4.y = f2bf(v.y); s4.z = f2bf(v.z); s4.w = f2bf(v.w);
  reinterpret_cast<ushort4*>(sh)[(size_t)u * 16 + c] = s4;
}

// ---------------------------------------------------------------------------
// CSR build, two-level binned counting sort.
// Stage A: coarse histograms (both directions in one pass).
// ---------------------------------------------------------------------------
__global__ __launch_bounds__(256) void k_coarse_hist(
    const int* __restrict__ s, const int* __restrict__ d,
    int* __restrict__ chm, int* __restrict__ chu, int E) {
  __shared__ int hm[NB_M];
  __shared__ int hu[NB_U];
  int t = threadIdx.x;
  for (int i = t; i < NB_M; i += 256) hm[i] = 0;
  for (int i = t; i < NB_U; i += 256) hu[i] = 0;
  __syncthreads();
  int base = blockIdx.x * 2048;
  for (int k = 0; k < 8; ++k) {
    int e = base + k * 256 + t;
    if (e < E) {
      atomicAdd(&hu[s[e] >> 8], 1);
      atomicAdd(&hm[d[e] >> 8], 1);
    }
  }
  __syncthreads();
  for (int i = t; i < NB_M; i += 256) if (hm[i]) atomicAdd(&chm[i], hm[i]);
  for (int i = t; i < NB_U; i += 256) if (hu[i]) atomicAdd(&chu[i], hu[i]);
}

// Stage B: scan coarse hists -> bucket segments (gseg) + partition cursors.
// Also writes rp_m[N_MOVIES] = rp_u[N_USERS] = E.
__global__ __launch_bounds__(512) void k_gseg_scan(
    const int* __restrict__ chm, const int* __restrict__ chu,
    int* __restrict__ gsegm, int* __restrict__ gsegu,
    int* __restrict__ gcurm, int* __restrict__ gcuru,
    int* __restrict__ rp_m, int* __restrict__ rp_u) {
  __shared__ int sh[512];
  int t = threadIdx.x;
  // movie buckets
  int v = (t < NB_M) ? chm[t] : 0;
  sh[t] = v; __syncthreads();
  int x = v;
  for (int off = 1; off < 512; off <<= 1) {
    int y = (t >= off) ? sh[t - off] : 0;
    __syncthreads();
    x += y; sh[t] = x;
    __syncthreads();
  }
  if (t < NB_M) { int ex = x - v; gsegm[t] = ex; gcurm[t] = ex; }
  if (t == 0) {
    gsegm[NB_M] = N_EDGES;
    rp_m[N_MOVIES] = N_EDGES;
    rp_u[N_USERS]  = N_EDGES;
  }
  __syncthreads();
  // user buckets
  v = (t < NB_U) ? chu[t] : 0;
  sh[t] = v; __syncthreads();
  x = v;
  for (int off = 1; off < 512; off <<= 1) {
    int y = (t >= off) ? sh[t - off] : 0;
    __syncthreads();
    x += y; sh[t] = x;
    __syncthreads();
  }
  if (t < NB_U) { int ex = x - v; gsegu[t] = ex; gcuru[t] = ex; }
  if (t == 0) gsegu[NB_U] = N_EDGES;
}

// Stage C: LDS-staged partition into bucket segments (coalesced runs).
// pairs[i] = (src << 32) | dst.
template <int NB, bool BY_DST>
__global__ __launch_bounds__(512) void k_part(
    const int* __restrict__ s, const int* __restrict__ d,
    int* __restrict__ gcur, unsigned long long* __restrict__ pairs, int E) {
  __shared__ int hist[NB];
  __shared__ int lstart[NB];
  __shared__ int lcur[NB];
  __shared__ int gbase[NB];
  __shared__ unsigned long long stage[PCHUNK];
  __shared__ unsigned short sbkt[PCHUNK];
  __shared__ int sh[512];
  int t = threadIdx.x;
  for (int i = t; i < NB; i += 512) hist[i] = 0;
  __syncthreads();
  int base = blockIdx.x * PCHUNK;
  int nloc = min(PCHUNK, E - base);
  int ss[8], dd[8];
#pragma unroll
  for (int k = 0; k < 8; ++k) {
    int e = base + k * 512 + t;
    if (e < E) {
      ss[k] = s[e]; dd[k] = d[e];
      int b = (BY_DST ? dd[k] : ss[k]) >> 8;
      atomicAdd(&hist[b], 1);
    }
  }
  __syncthreads();
  // exclusive scan of hist (NB <= 512)
  int v = (t < NB) ? hist[t] : 0;
  sh[t] = v; __syncthreads();
  int x = v;
  for (int off = 1; off < 512; off <<= 1) {
    int y = (t >= off) ? sh[t - off] : 0;
    __syncthreads();
    x += y; sh[t] = x;
    __syncthreads();
  }
  if (t < NB) {
    int ex = x - v;
    lstart[t] = ex;
    lcur[t] = ex;
    gbase[t] = (v > 0) ? atomicAdd(&gcur[t], v) : 0;
  }
  __syncthreads();
#pragma unroll
  for (int k = 0; k < 8; ++k) {
    int e = base + k * 512 + t;
    if (e < E) {
      int b = (BY_DST ? dd[k] : ss[k]) >> 8;
      int pos = atomicAdd(&lcur[b], 1);
      stage[pos] = ((unsigned long long)(unsigned)ss[k] << 32) | (unsigned)dd[k];
      sbkt[pos] = (unsigned short)b;
    }
  }
  __syncthreads();
  for (int p = t; p < nloc; p += 512) {
    int b = sbkt[p];
    pairs[gbase[b] + (p - lstart[b])] = stage[p];
  }
}

// Stage D: per-bucket fill. One block per bucket: LDS-count the 256 node ids,
// LDS scan -> rp (coalesced write), then scatter col within the bucket's
// L2-resident window. Produces rp so no separate count/scan pass is needed.
template <bool BY_DST>
__global__ __launch_bounds__(512) void k_fill_bucket(
    const unsigned long long* __restrict__ pairs,
    const int* __restrict__ gseg, int* __restrict__ rp,
    void* __restrict__ col, int nNodes) {
  __shared__ int cnt[256];
  __shared__ int rploc[256];   // exclusive scan -> then scatter cursor
  __shared__ int sh[256];
  int t = threadIdx.x;
  if (t < 256) cnt[t] = 0;
  __syncthreads();
  int b = blockIdx.x;
  int begin = gseg[b], end = gseg[b + 1];
  for (int i = begin + t; i < end; i += 512) {
    unsigned long long pr = pairs[i];
    int key = BY_DST ? (int)(pr & 0xffffffffu) : (int)(pr >> 32);
    atomicAdd(&cnt[key & 255], 1);
  }
  __syncthreads();
  int v = (t < 256) ? cnt[t] : 0;
  if (t < 256) sh[t] = v;
  __syncthreads();
  int x = v;
  for (int off = 1; off < 256; off <<= 1) {
    int y = (t >= off && t < 256) ? sh[t - off] : 0;
    __syncthreads();
    if (t < 256) { x += y; sh[t] = x; }
    __syncthreads();
  }
  if (t < 256) {
    int ex = x - v;
    rploc[t] = begin + ex;
    int node = b * 256 + t;
    if (node < nNodes) rp[node] = begin + ex;
  }
  __syncthreads();
  for (int i = begin + t; i < end; i += 512) {
    unsigned long long pr = pairs[i];
    int sval = (int)(pr >> 32), dval = (int)(pr & 0xffffffffu);
    int key = BY_DST ? dval : sval;
    int payload = BY_DST ? sval : dval;
    int pos = atomicAdd(&rploc[key & 255], 1);
    if (BY_DST) ((int*)col)[pos] = payload;
    else ((unsigned short*)col)[pos] = (unsigned short)payload;
  }
}

// ---------------------------------------------------------------------------
// Aggregation from bf16 shadow: wave per dst node. Lane = (g, q): g = edge
// subgroup (4 edges in flight), q = ushort4 quad (4 feats). No LDS, tiny
// VGPR -> full occupancy. Mean written (f32) in place.
// ---------------------------------------------------------------------------
template <typename IdxT>
__global__ __launch_bounds__(256) void k_agg_mean(
    const unsigned short* __restrict__ xsrc_bf, const int* __restrict__ rp,
    const IdxT* __restrict__ col, float* __restrict__ mean_out, int n) {
  int t = threadIdx.x;
  int slot = t >> 6, lane = t & 63;
  int q = lane & 15, g = lane >> 4;
  int node = blockIdx.x * 4 + slot;        // n % 4 == 0
  int e0 = rp[node], e1 = rp[node + 1];
  float4 acc = {0.f, 0.f, 0.f, 0.f};
  int e = e0 + g;
  int s_next = (e < e1) ? (int)col[e] : 0;
  while (e < e1) {
    int s = s_next;
    int en = e + 4;
    if (en < e1) s_next = (int)col[en];    // prefetch next index
    ushort4 v = reinterpret_cast<const ushort4*>(xsrc_bf)[(size_t)s * 16 + q];
    acc.x += bf2f(v.x); acc.y += bf2f(v.y);
    acc.z += bf2f(v.z); acc.w += bf2f(v.w);
    e = en;
  }
  acc.x += __shfl_xor(acc.x, 32, 64); acc.y += __shfl_xor(acc.y, 32, 64);
  acc.z += __shfl_xor(acc.z, 32, 64); acc.w += __shfl_xor(acc.w, 32, 64);
  acc.x += __shfl_xor(acc.x, 16, 64); acc.y += __shfl_xor(acc.y, 16, 64);
  acc.z += __shfl_xor(acc.z, 16, 64); acc.w += __shfl_xor(acc.w, 16, 64);
  if (g == 0) {
    float inv = 1.0f / fmaxf((float)(e1 - e0), 1.0f);
    acc.x *= inv; acc.y *= inv; acc.z *= inv; acc.w *= inv;
    reinterpret_cast<float4*>(mean_out)[(size_t)node * 16 + q] = acc;
  }
}

// ---------------------------------------------------------------------------
// Linear part, IN PLACE: io = relu?( io @ Wl.T + bl + xdst @ Wr.T ).
// Optionally writes a bf16 shadow (for the next layer's gather).
// ---------------------------------------------------------------------------
template <bool RELU>
__global__ __launch_bounds__(256) void k_sage_lin(
    float* __restrict__ io, const float* __restrict__ xdst,
    const float* __restrict__ Wl, const float* __restrict__ bl,
    const float* __restrict__ Wr, unsigned short* __restrict__ sh_out, int n) {
  __shared__ float WlT[HIDDEN * 65];
  __shared__ float WrT[HIDDEN * 65];
  __shared__ float rowA[4][HIDDEN];
  __shared__ float rowX[4][HIDDEN];
  int t = threadIdx.x;
  for (int idx = t; idx < HIDDEN * HIDDEN; idx += 256) {
    int h = idx >> 6, k = idx & 63;
    WlT[k * 65 + h] = Wl[idx];
    WrT[k * 65 + h] = Wr[idx];
  }
  int slot = t >> 6, h = t & 63;
  int node = blockIdx.x * 4 + slot;        // n % 4 == 0, grid exact
  rowA[slot][h] = io[(size_t)node * HIDDEN + h];
  rowX[slot][h] = xdst[(size_t)node * HIDDEN + h];
  __syncthreads();
  float accL = 0.f, accR = 0.f;
#pragma unroll
  for (int k = 0; k < HIDDEN; ++k) {
    accL += rowA[slot][k] * WlT[k * 65 + h];
    accR += rowX[slot][k] * WrT[k * 65 + h];
  }
  float r = accL + bl[h] + accR;
  if (RELU) r = fmaxf(r, 0.f);
  io[(size_t)node * HIDDEN + h] = r;
  if (sh_out) sh_out[(size_t)node * HIDDEN + h] = f2bf(r);
}

// ---------------------------------------------------------------------------
// Decoder: 16 lanes per label edge (float4), 4 labels per wave. f32 tables.
// ---------------------------------------------------------------------------
__global__ __launch_bounds__(256) void k_decode(
    const float* __restrict__ ou, const float* __restrict__ om,
    const int* __restrict__ ls, const int* __restrict__ ld,
    float* __restrict__ out, int L) {
  int gid = blockIdx.x * 256 + threadIdx.x;
  int lab = gid >> 4, q = gid & 15;
  if (lab >= L) return;
  float4 a = reinterpret_cast<const float4*>(ou)[(size_t)ls[lab] * 16 + q];
  float4 b = reinterpret_cast<const float4*>(om)[(size_t)ld[lab] * 16 + q];
  float s = a.x * b.x + a.y * b.y + a.z * b.z + a.w * b.w;
  s += __shfl_xor(s, 1, 64);
  s += __shfl_xor(s, 2, 64);
  s += __shfl_xor(s, 4, 64);
  s += __shfl_xor(s, 8, 64);
  if (q == 0) out[lab] = s;
}

// ---------------------------------------------------------------------------
extern "C" void kernel_launch(void* const* d_in, const int* in_sizes, int n_in,
                              void* d_out, int out_size, void* d_ws, size_t ws_size,
                              hipStream_t stream) {
  const float* movie_x        = (const float*)d_in[0];
  const int*   user_node_id   = (const int*)d_in[1];
  const int*   movie_node_id  = (const int*)d_in[2];
  const int*   edge_src_user  = (const int*)d_in[3];
  const int*   edge_dst_movie = (const int*)d_in[4];
  const int*   label_src_user = (const int*)d_in[5];
  const int*   label_dst_movie= (const int*)d_in[6];
  const float* user_emb  = (const float*)d_in[7];
  const float* movie_emb = (const float*)d_in[8];
  const float* lin_W     = (const float*)d_in[9];
  const float* lin_b     = (const float*)d_in[10];
  const float* W_l_um1 = (const float*)d_in[11];
  const float* b_l_um1 = (const float*)d_in[12];
  const float* W_r_um1 = (const float*)d_in[13];
  const float* W_l_mu1 = (const float*)d_in[14];
  const float* b_l_mu1 = (const float*)d_in[15];
  const float* W_r_mu1 = (const float*)d_in[16];
  const float* W_l_um2 = (const float*)d_in[17];
  const float* b_l_um2 = (const float*)d_in[18];
  const float* W_r_um2 = (const float*)d_in[19];
  const float* W_l_mu2 = (const float*)d_in[20];
  const float* b_l_mu2 = (const float*)d_in[21];
  const float* W_r_mu2 = (const float*)d_in[22];
  float* out = (float*)d_out;

  // workspace layout: f32 tables, bf16 shadows, then CSR ints (~119 MB).
  // pairs (16 MB) aliases B_user, which is dead until layer 1.
  float* ws = (float*)d_ws;
  const size_t UH = (size_t)N_USERS * HIDDEN;    // 6.4M elems
  const size_t MH = (size_t)N_MOVIES * HIDDEN;   // 3.2M elems
  float* A_user  = ws;                  // x_user  -> later o_user
  float* A_movie = A_user + UH;         // x_movie -> later o_movie
  float* B_user  = A_movie + MH;        // mean -> h_user (in place)
  float* B_movie = B_user + UH;         // mean -> h_movie (in place)
  unsigned short* xu_sh = (unsigned short*)(B_movie + MH);  // [UH] also hu_sh
  unsigned short* xm_sh = xu_sh + UH;   // [MH]
  unsigned short* hm_sh = xm_sh + MH;   // [MH]
  unsigned short* hu_sh = xu_sh;        // reuse (xu_sh dead after layer-1 aggs)
  int* col_m = (int*)(hm_sh + MH);                            // [N_EDGES]
  unsigned short* col_u = (unsigned short*)(col_m + N_EDGES); // [N_EDGES] u16
  int* rp_m  = (int*)(col_u + N_EDGES);  // [N_MOVIES+1]
  int* rp_u  = rp_m + (N_MOVIES + 1);    // [N_USERS+1]
  int* chm   = rp_u + (N_USERS + 1);     // [NB_M]
  int* chu   = chm + NB_M;               // [NB_U]
  int* gsegm = chu + NB_U;               // [NB_M+1]
  int* gsegu = gsegm + (NB_M + 1);       // [NB_U+1]
  int* gcurm = gsegu + (NB_U + 1);       // [NB_M]
  int* gcuru = gcurm + NB_M;             // [NB_U]
  unsigned long long* pairs = (unsigned long long*)B_user;    // aliased, 16 MB

  const int HB = (N_EDGES + 2047) / 2048;       // 977  coarse-hist blocks
  const int PB = (N_EDGES + PCHUNK - 1) / PCHUNK; // 489 partition blocks

  // feature init (+ bf16 shadows)
  k_xmovie<<<N_MOVIES / 4, 256, 0, stream>>>(movie_x, movie_node_id, movie_emb,
                                             lin_W, lin_b, A_movie, xm_sh);
  k_gather_user<<<(N_USERS * 16) / 256, 256, 0, stream>>>(user_emb, user_node_id,
                                                          A_user, xu_sh, N_USERS);

  // CSR build: coarse hist -> segment scan -> partition -> bucket fill.
  hipMemsetAsync(chm, 0, (NB_M + NB_U) * sizeof(int), stream);
  k_coarse_hist<<<HB, 256, 0, stream>>>(edge_src_user, edge_dst_movie, chm, chu, N_EDGES);
  k_gseg_scan<<<1, 512, 0, stream>>>(chm, chu, gsegm, gsegu, gcurm, gcuru, rp_m, rp_u);
  k_part<NB_M, true><<<PB, 512, 0, stream>>>(edge_src_user, edge_dst_movie,
                                             gcurm, pairs, N_EDGES);
  k_fill_bucket<true><<<NB_M, 512, 0, stream>>>(pairs, gsegm, rp_m, col_m, N_MOVIES);
  k_part<NB_U, false><<<PB, 512, 0, stream>>>(edge_src_user, edge_dst_movie,
                                              gcuru, pairs, N_EDGES);
  k_fill_bucket<false><<<NB_U, 512, 0, stream>>>(pairs, gsegu, rp_u, col_u, N_USERS);

  // layer 1 (+relu): mean into B_*, in-place linear (h shadows out)
  k_agg_mean<int><<<N_MOVIES / 4, 256, 0, stream>>>(xu_sh, rp_m, col_m, B_movie, N_MOVIES);
  k_sage_lin<true><<<N_MOVIES / 4, 256, 0, stream>>>(B_movie, A_movie,
                                                     W_l_um1, b_l_um1, W_r_um1, hm_sh, N_MOVIES);
  k_agg_mean<unsigned short><<<N_USERS / 4, 256, 0, stream>>>(xm_sh, rp_u, col_u, B_user, N_USERS);
  k_sage_lin<true><<<N_USERS / 4, 256, 0, stream>>>(B_user, A_user,
                                                    W_l_mu1, b_l_mu1, W_r_mu1, hu_sh, N_USERS);

  // layer 2 (no activation): mean into A_* (x_* dead), in-place linear
  k_agg_mean<int><<<N_MOVIES / 4, 256, 0, stream>>>(hu_sh, rp_m, col_m, A_movie, N_MOVIES);
  k_sage_lin<false><<<N_MOVIES / 4, 256, 0, stream>>>(A_movie, B_movie,
                                                      W_l_um2, b_l_um2, W_r_um2, nullptr, N_MOVIES);
  k_agg_mean<unsigned short><<<N_USERS / 4, 256, 0, stream>>>(hm_sh, rp_u, col_u, A_user, N_USERS);
  k_sage_lin<false><<<N_USERS / 4, 256, 0, stream>>>(A_user, B_user,
                                                     W_l_mu2, b_l_mu2, W_r_mu2, nullptr, N_USERS);

  // decoder (f32 tables)
  k_decode<<<(N_LABEL * 16) / 256, 256, 0, stream>>>(
      A_user, A_movie, label_src_user, label_dst_movie, out, N_LABEL);
}

// Round 13
// 579.967 us; speedup vs baseline: 13.0665x; 1.4291x over previous
//
#include <hip/hip_runtime.h>
#include <hip/hip_bf16.h>

// Problem constants (fixed by reference)
#define HIDDEN   64
#define N_USERS  100000
#define N_MOVIES 50000
#define MFEAT    128
#define N_EDGES  2000000
#define N_LABEL  500000

#define NB_M 196     // ceil(50000/256)  coarse buckets by movie id >> 8
#define NB_U 391     // ceil(100000/256) coarse buckets by user id >> 8
#define PCHUNK 4096  // edges per partition block (512 thr x 8)

typedef __attribute__((ext_vector_type(8))) short bfrag8;  // 8 bf16 (4 VGPR)
typedef __attribute__((ext_vector_type(4))) float f32x4;   // MFMA accumulator

// bf16 helpers (RNE; inputs finite)
__device__ __forceinline__ float bf2f(unsigned short u) {
  union { unsigned int i; float f; } c; c.i = ((unsigned int)u) << 16; return c.f;
}
__device__ __forceinline__ unsigned short f2bf(float x) {
  union { float f; unsigned int i; } c; c.f = x;
  unsigned int r = c.i + 0x7FFFu + ((c.i >> 16) & 1u);
  return (unsigned short)(r >> 16);
}

// ---------------------------------------------------------------------------
// Kernel 1: x_movie = movie_x @ lin_W.T + lin_b + movie_emb[movie_node_id]
// bf16 output only (the whole downstream pipeline consumes bf16).
// ---------------------------------------------------------------------------
__global__ __launch_bounds__(256) void k_xmovie(
    const float* __restrict__ movie_x, const int* __restrict__ movie_node_id,
    const float* __restrict__ emb, const float* __restrict__ W,
    const float* __restrict__ b, unsigned short* __restrict__ out_bf) {
  __shared__ float Wt[MFEAT * 65];   // Wt[f*65+h] = W[h*128+f]
  __shared__ float row[4][MFEAT];
  int t = threadIdx.x;
  for (int idx = t; idx < HIDDEN * MFEAT; idx += 256) {
    int h = idx >> 7, f = idx & 127;
    Wt[f * 65 + h] = W[idx];
  }
  __syncthreads();
  int slot = t >> 6, h = t & 63;
  int m = blockIdx.x * 4 + slot;           // 50000/4 = 12500 exact
  row[slot][h]      = movie_x[(size_t)m * MFEAT + h];
  row[slot][h + 64] = movie_x[(size_t)m * MFEAT + 64 + h];
  float acc = b[h] + emb[(size_t)movie_node_id[m] * HIDDEN + h];
#pragma unroll 8
  for (int f = 0; f < MFEAT; ++f) acc += row[slot][f] * Wt[f * 65 + h];
  out_bf[(size_t)m * HIDDEN + h] = f2bf(acc);
}

// ---------------------------------------------------------------------------
// Kernel 2: x_user = bf16(user_emb[user_node_id])
// ---------------------------------------------------------------------------
__global__ __launch_bounds__(256) void k_gather_user(
    const float* __restrict__ emb, const int* __restrict__ nid,
    unsigned short* __restrict__ out_bf, int n) {
  int gid = blockIdx.x * 256 + threadIdx.x;
  int u = gid >> 4, c = gid & 15;
  if (u >= n) return;
  float4 v = reinterpret_cast<const float4*>(emb)[(size_t)nid[u] * 16 + c];
  ushort4 s4;
  s4.x = f2bf(v.x); s4.y = f2bf(v.y); s4.z = f2bf(v.z); s4.w = f2bf(v.w);
  reinterpret_cast<ushort4*>(out_bf)[(size_t)u * 16 + c] = s4;
}

// ---------------------------------------------------------------------------
// CSR build, two-level binned counting sort (as round 7, unchanged).
// ---------------------------------------------------------------------------
__global__ __launch_bounds__(256) void k_coarse_hist(
    const int* __restrict__ s, const int* __restrict__ d,
    int* __restrict__ chm, int* __restrict__ chu, int E) {
  __shared__ int hm[NB_M];
  __shared__ int hu[NB_U];
  int t = threadIdx.x;
  for (int i = t; i < NB_M; i += 256) hm[i] = 0;
  for (int i = t; i < NB_U; i += 256) hu[i] = 0;
  __syncthreads();
  int base = blockIdx.x * 2048;
  for (int k = 0; k < 8; ++k) {
    int e = base + k * 256 + t;
    if (e < E) {
      atomicAdd(&hu[s[e] >> 8], 1);
      atomicAdd(&hm[d[e] >> 8], 1);
    }
  }
  __syncthreads();
  for (int i = t; i < NB_M; i += 256) if (hm[i]) atomicAdd(&chm[i], hm[i]);
  for (int i = t; i < NB_U; i += 256) if (hu[i]) atomicAdd(&chu[i], hu[i]);
}

__global__ __launch_bounds__(512) void k_gseg_scan(
    const int* __restrict__ chm, const int* __restrict__ chu,
    int* __restrict__ gsegm, int* __restrict__ gsegu,
    int* __restrict__ gcurm, int* __restrict__ gcuru,
    int* __restrict__ rp_m, int* __restrict__ rp_u) {
  __shared__ int sh[512];
  int t = threadIdx.x;
  int v = (t < NB_M) ? chm[t] : 0;
  sh[t] = v; __syncthreads();
  int x = v;
  for (int off = 1; off < 512; off <<= 1) {
    int y = (t >= off) ? sh[t - off] : 0;
    __syncthreads();
    x += y; sh[t] = x;
    __syncthreads();
  }
  if (t < NB_M) { int ex = x - v; gsegm[t] = ex; gcurm[t] = ex; }
  if (t == 0) {
    gsegm[NB_M] = N_EDGES;
    rp_m[N_MOVIES] = N_EDGES;
    rp_u[N_USERS]  = N_EDGES;
  }
  __syncthreads();
  v = (t < NB_U) ? chu[t] : 0;
  sh[t] = v; __syncthreads();
  x = v;
  for (int off = 1; off < 512; off <<= 1) {
    int y = (t >= off) ? sh[t - off] : 0;
    __syncthreads();
    x += y; sh[t] = x;
    __syncthreads();
  }
  if (t < NB_U) { int ex = x - v; gsegu[t] = ex; gcuru[t] = ex; }
  if (t == 0) gsegu[NB_U] = N_EDGES;
}

template <int NB, bool BY_DST>
__global__ __launch_bounds__(512) void k_part(
    const int* __restrict__ s, const int* __restrict__ d,
    int* __restrict__ gcur, unsigned long long* __restrict__ pairs, int E) {
  __shared__ int hist[NB];
  __shared__ int lstart[NB];
  __shared__ int lcur[NB];
  __shared__ int gbase[NB];
  __shared__ unsigned long long stage[PCHUNK];
  __shared__ unsigned short sbkt[PCHUNK];
  __shared__ int sh[512];
  int t = threadIdx.x;
  for (int i = t; i < NB; i += 512) hist[i] = 0;
  __syncthreads();
  int base = blockIdx.x * PCHUNK;
  int nloc = min(PCHUNK, E - base);
  int ss[8], dd[8];
#pragma unroll
  for (int k = 0; k < 8; ++k) {
    int e = base + k * 512 + t;
    if (e < E) {
      ss[k] = s[e]; dd[k] = d[e];
      int b = (BY_DST ? dd[k] : ss[k]) >> 8;
      atomicAdd(&hist[b], 1);
    }
  }
  __syncthreads();
  int v = (t < NB) ? hist[t] : 0;
  sh[t] = v; __syncthreads();
  int x = v;
  for (int off = 1; off < 512; off <<= 1) {
    int y = (t >= off) ? sh[t - off] : 0;
    __syncthreads();
    x += y; sh[t] = x;
    __syncthreads();
  }
  if (t < NB) {
    int ex = x - v;
    lstart[t] = ex;
    lcur[t] = ex;
    gbase[t] = (v > 0) ? atomicAdd(&gcur[t], v) : 0;
  }
  __syncthreads();
#pragma unroll
  for (int k = 0; k < 8; ++k) {
    int e = base + k * 512 + t;
    if (e < E) {
      int b = (BY_DST ? dd[k] : ss[k]) >> 8;
      int pos = atomicAdd(&lcur[b], 1);
      stage[pos] = ((unsigned long long)(unsigned)ss[k] << 32) | (unsigned)dd[k];
      sbkt[pos] = (unsigned short)b;
    }
  }
  __syncthreads();
  for (int p = t; p < nloc; p += 512) {
    int b = sbkt[p];
    pairs[gbase[b] + (p - lstart[b])] = stage[p];
  }
}

template <bool BY_DST>
__global__ __launch_bounds__(512) void k_fill_bucket(
    const unsigned long long* __restrict__ pairs,
    const int* __restrict__ gseg, int* __restrict__ rp,
    void* __restrict__ col, int nNodes) {
  __shared__ int cnt[256];
  __shared__ int rploc[256];
  __shared__ int sh[256];
  int t = threadIdx.x;
  if (t < 256) cnt[t] = 0;
  __syncthreads();
  int b = blockIdx.x;
  int begin = gseg[b], end = gseg[b + 1];
  for (int i = begin + t; i < end; i += 512) {
    unsigned long long pr = pairs[i];
    int key = BY_DST ? (int)(pr & 0xffffffffu) : (int)(pr >> 32);
    atomicAdd(&cnt[key & 255], 1);
  }
  __syncthreads();
  int v = (t < 256) ? cnt[t] : 0;
  if (t < 256) sh[t] = v;
  __syncthreads();
  int x = v;
  for (int off = 1; off < 256; off <<= 1) {
    int y = (t >= off && t < 256) ? sh[t - off] : 0;
    __syncthreads();
    if (t < 256) { x += y; sh[t] = x; }
    __syncthreads();
  }
  if (t < 256) {
    int ex = x - v;
    rploc[t] = begin + ex;
    int node = b * 256 + t;
    if (node < nNodes) rp[node] = begin + ex;
  }
  __syncthreads();
  for (int i = begin + t; i < end; i += 512) {
    unsigned long long pr = pairs[i];
    int sval = (int)(pr >> 32), dval = (int)(pr & 0xffffffffu);
    int key = BY_DST ? dval : sval;
    int payload = BY_DST ? sval : dval;
    int pos = atomicAdd(&rploc[key & 255], 1);
    if (BY_DST) ((int*)col)[pos] = payload;
    else ((unsigned short*)col)[pos] = (unsigned short)payload;
  }
}

// ---------------------------------------------------------------------------
// Aggregation (bf16 in, bf16 mean out): wave per dst node. Lane = (g, q).
// f32 accumulate, mean quantized to bf16 on store.
// ---------------------------------------------------------------------------
template <typename IdxT>
__global__ __launch_bounds__(256) void k_agg_mean(
    const unsigned short* __restrict__ xsrc_bf, const int* __restrict__ rp,
    const IdxT* __restrict__ col, unsigned short* __restrict__ mean_bf, int n) {
  int t = threadIdx.x;
  int slot = t >> 6, lane = t & 63;
  int q = lane & 15, g = lane >> 4;
  int node = blockIdx.x * 4 + slot;        // n % 4 == 0
  int e0 = rp[node], e1 = rp[node + 1];
  float4 acc = {0.f, 0.f, 0.f, 0.f};
  int e = e0 + g;
  int s_next = (e < e1) ? (int)col[e] : 0;
  while (e < e1) {
    int s = s_next;
    int en = e + 4;
    if (en < e1) s_next = (int)col[en];    // prefetch next index
    ushort4 v = reinterpret_cast<const ushort4*>(xsrc_bf)[(size_t)s * 16 + q];
    acc.x += bf2f(v.x); acc.y += bf2f(v.y);
    acc.z += bf2f(v.z); acc.w += bf2f(v.w);
    e = en;
  }
  acc.x += __shfl_xor(acc.x, 32, 64); acc.y += __shfl_xor(acc.y, 32, 64);
  acc.z += __shfl_xor(acc.z, 32, 64); acc.w += __shfl_xor(acc.w, 32, 64);
  acc.x += __shfl_xor(acc.x, 16, 64); acc.y += __shfl_xor(acc.y, 16, 64);
  acc.z += __shfl_xor(acc.z, 16, 64); acc.w += __shfl_xor(acc.w, 16, 64);
  if (g == 0) {
    float inv = 1.0f / fmaxf((float)(e1 - e0), 1.0f);
    ushort4 sv;
    sv.x = f2bf(acc.x * inv); sv.y = f2bf(acc.y * inv);
    sv.z = f2bf(acc.z * inv); sv.w = f2bf(acc.w * inv);
    reinterpret_cast<ushort4*>(mean_bf)[(size_t)node * 16 + q] = sv;
  }
}

// ---------------------------------------------------------------------------
// MFMA linear: out[node,h] = [mean | xdst] @ [Wl;Wr]^T + bl  (+relu).
// Wave computes a 16-node x 64-h tile via 16x16x32 bf16 MFMA (K=128 in 4
// chunks). B-frags packed once per block in LDS, hoisted to VGPRs.
// Verified layouts (learn_hip m89): A row=lane&15, k=(lane>>4)*8+i;
// B col=lane&15, same k; C/D row=(lane>>4)*4+reg, col=lane&15.
// ---------------------------------------------------------------------------
template <bool RELU, bool OUT_F32>
__global__ __launch_bounds__(256) void k_lin_mfma(
    const unsigned short* __restrict__ A,    // mean [n][64] bf16
    const unsigned short* __restrict__ X,    // xdst [n][64] bf16
    const float* __restrict__ Wl, const float* __restrict__ bl,
    const float* __restrict__ Wr, void* __restrict__ outp, int n) {
  __shared__ short pack[4][4][64][8];        // [kc][ht][lane][i]
  int t = threadIdx.x;
  // stage packed B frags: thread t fills (kc=j, ht=t>>6, l=t&63)
  {
    int ht = t >> 6, l = t & 63;
    int h = ht * 16 + (l & 15);
    int ksub = (l >> 4) << 3;
#pragma unroll
    for (int j = 0; j < 4; ++j) {
      const float* Wsrc = (j < 2 ? Wl : Wr) + (size_t)h * HIDDEN + ((j & 1) ? 32 : 0) + ksub;
      bfrag8 fr;
#pragma unroll
      for (int i = 0; i < 8; ++i) fr[i] = (short)f2bf(Wsrc[i]);
      *reinterpret_cast<bfrag8*>(&pack[j][ht][l][0]) = fr;
    }
  }
  __syncthreads();
  int wid = t >> 6, l = t & 63;
  bfrag8 bfr[4][4];
#pragma unroll
  for (int kc = 0; kc < 4; ++kc)
#pragma unroll
    for (int ht = 0; ht < 4; ++ht)
      bfr[kc][ht] = *reinterpret_cast<const bfrag8*>(&pack[kc][ht][l][0]);
  float bias[4];
#pragma unroll
  for (int ht = 0; ht < 4; ++ht) bias[ht] = bl[ht * 16 + (l & 15)];
  int ntiles = n >> 4;                        // n % 16 == 0
  int arow = l & 15, acol = (l >> 4) << 3;    // A k-offset within 32-chunk
  f32x4 zero = {0.f, 0.f, 0.f, 0.f};
  for (int tile = blockIdx.x * 4 + wid; tile < ntiles; tile += gridDim.x * 4) {
    int node0 = tile << 4;
    const unsigned short* pA = A + (size_t)(node0 + arow) * HIDDEN + acol;
    const unsigned short* pX = X + (size_t)(node0 + arow) * HIDDEN + acol;
    bfrag8 afr[4];
    afr[0] = *reinterpret_cast<const bfrag8*>(pA);
    afr[1] = *reinterpret_cast<const bfrag8*>(pA + 32);
    afr[2] = *reinterpret_cast<const bfrag8*>(pX);
    afr[3] = *reinterpret_cast<const bfrag8*>(pX + 32);
    f32x4 acc[4];
    acc[0] = zero; acc[1] = zero; acc[2] = zero; acc[3] = zero;
#pragma unroll
    for (int kc = 0; kc < 4; ++kc)
#pragma unroll
      for (int ht = 0; ht < 4; ++ht)
        acc[ht] = __builtin_amdgcn_mfma_f32_16x16x32_bf16(afr[kc], bfr[kc][ht],
                                                          acc[ht], 0, 0, 0);
#pragma unroll
    for (int ht = 0; ht < 4; ++ht) {
      int h = ht * 16 + (l & 15);
#pragma unroll
      for (int r = 0; r < 4; ++r) {
        int node = node0 + ((l >> 4) << 2) + r;
        float v = acc[ht][r] + bias[ht];
        if (RELU) v = fmaxf(v, 0.f);
        if (OUT_F32) ((float*)outp)[(size_t)node * HIDDEN + h] = v;
        else ((unsigned short*)outp)[(size_t)node * HIDDEN + h] = f2bf(v);
      }
    }
  }
}

// ---------------------------------------------------------------------------
// Decoder: 16 lanes per label edge (float4), 4 labels per wave. f32 tables.
// ---------------------------------------------------------------------------
__global__ __launch_bounds__(256) void k_decode(
    const float* __restrict__ ou, const float* __restrict__ om,
    const int* __restrict__ ls, const int* __restrict__ ld,
    float* __restrict__ out, int L) {
  int gid = blockIdx.x * 256 + threadIdx.x;
  int lab = gid >> 4, q = gid & 15;
  if (lab >= L) return;
  float4 a = reinterpret_cast<const float4*>(ou)[(size_t)ls[lab] * 16 + q];
  float4 b = reinterpret_cast<const float4*>(om)[(size_t)ld[lab] * 16 + q];
  float s = a.x * b.x + a.y * b.y + a.z * b.z + a.w * b.w;
  s += __shfl_xor(s, 1, 64);
  s += __shfl_xor(s, 2, 64);
  s += __shfl_xor(s, 4, 64);
  s += __shfl_xor(s, 8, 64);
  if (q == 0) out[lab] = s;
}

// ---------------------------------------------------------------------------
extern "C" void kernel_launch(void* const* d_in, const int* in_sizes, int n_in,
                              void* d_out, int out_size, void* d_ws, size_t ws_size,
                              hipStream_t stream) {
  const float* movie_x        = (const float*)d_in[0];
  const int*   user_node_id   = (const int*)d_in[1];
  const int*   movie_node_id  = (const int*)d_in[2];
  const int*   edge_src_user  = (const int*)d_in[3];
  const int*   edge_dst_movie = (const int*)d_in[4];
  const int*   label_src_user = (const int*)d_in[5];
  const int*   label_dst_movie= (const int*)d_in[6];
  const float* user_emb  = (const float*)d_in[7];
  const float* movie_emb = (const float*)d_in[8];
  const float* lin_W     = (const float*)d_in[9];
  const float* lin_b     = (const float*)d_in[10];
  const float* W_l_um1 = (const float*)d_in[11];
  const float* b_l_um1 = (const float*)d_in[12];
  const float* W_r_um1 = (const float*)d_in[13];
  const float* W_l_mu1 = (const float*)d_in[14];
  const float* b_l_mu1 = (const float*)d_in[15];
  const float* W_r_mu1 = (const float*)d_in[16];
  const float* W_l_um2 = (const float*)d_in[17];
  const float* b_l_um2 = (const float*)d_in[18];
  const float* W_r_um2 = (const float*)d_in[19];
  const float* W_l_mu2 = (const float*)d_in[20];
  const float* b_l_mu2 = (const float*)d_in[21];
  const float* W_r_mu2 = (const float*)d_in[22];
  float* out = (float*)d_out;

  // workspace layout (~103 MB): f32 decoder tables, bf16 pipeline, CSR ints.
  // pairs (16 MB) aliases o_user (dead until the final lin).
  float* ws = (float*)d_ws;
  const size_t UH = (size_t)N_USERS * HIDDEN;    // 6.4M elems
  const size_t MH = (size_t)N_MOVIES * HIDDEN;   // 3.2M elems
  float* o_user  = ws;                   // [UH] f32 (decoder)
  float* o_movie = o_user + UH;          // [MH] f32 (decoder)
  unsigned short* xu = (unsigned short*)(o_movie + MH);  // [UH] bf16
  unsigned short* xm = xu + UH;          // [MH]
  unsigned short* mu = xm + MH;          // [UH] mean (both layers)
  unsigned short* mm = mu + UH;          // [MH] mean (both layers)
  unsigned short* hu = mm + MH;          // [UH]
  unsigned short* hm = hu + UH;          // [MH]
  int* col_m = (int*)(hm + MH);                               // [N_EDGES]
  unsigned short* col_u = (unsigned short*)(col_m + N_EDGES); // [N_EDGES] u16
  int* rp_m  = (int*)(col_u + N_EDGES);  // [N_MOVIES+1]
  int* rp_u  = rp_m + (N_MOVIES + 1);    // [N_USERS+1]
  int* chm   = rp_u + (N_USERS + 1);     // [NB_M]
  int* chu   = chm + NB_M;               // [NB_U]
  int* gsegm = chu + NB_U;               // [NB_M+1]
  int* gsegu = gsegm + (NB_M + 1);       // [NB_U+1]
  int* gcurm = gsegu + (NB_U + 1);       // [NB_M]
  int* gcuru = gcurm + NB_M;             // [NB_U]
  unsigned long long* pairs = (unsigned long long*)o_user;    // aliased, 16 MB

  const int HB = (N_EDGES + 2047) / 2048;         // 977
  const int PB = (N_EDGES + PCHUNK - 1) / PCHUNK; // 489
  const int LM = (N_MOVIES / 16 + 3) / 4;         // 782  lin blocks (movie)
  const int LU = (N_USERS  / 16 + 3) / 4;         // 1563 lin blocks (user)

  // feature init (bf16)
  k_xmovie<<<N_MOVIES / 4, 256, 0, stream>>>(movie_x, movie_node_id, movie_emb,
                                             lin_W, lin_b, xm);
  k_gather_user<<<(N_USERS * 16) / 256, 256, 0, stream>>>(user_emb, user_node_id,
                                                          xu, N_USERS);

  // CSR build: coarse hist -> segment scan -> partition -> bucket fill.
  hipMemsetAsync(chm, 0, (NB_M + NB_U) * sizeof(int), stream);
  k_coarse_hist<<<HB, 256, 0, stream>>>(edge_src_user, edge_dst_movie, chm, chu, N_EDGES);
  k_gseg_scan<<<1, 512, 0, stream>>>(chm, chu, gsegm, gsegu, gcurm, gcuru, rp_m, rp_u);
  k_part<NB_M, true><<<PB, 512, 0, stream>>>(edge_src_user, edge_dst_movie,
                                             gcurm, pairs, N_EDGES);
  k_fill_bucket<true><<<NB_M, 512, 0, stream>>>(pairs, gsegm, rp_m, col_m, N_MOVIES);
  k_part<NB_U, false><<<PB, 512, 0, stream>>>(edge_src_user, edge_dst_movie,
                                              gcuru, pairs, N_EDGES);
  k_fill_bucket<false><<<NB_U, 512, 0, stream>>>(pairs, gsegu, rp_u, col_u, N_USERS);

  // layer 1 (+relu)
  k_agg_mean<int><<<N_MOVIES / 4, 256, 0, stream>>>(xu, rp_m, col_m, mm, N_MOVIES);
  k_lin_mfma<true, false><<<LM, 256, 0, stream>>>(mm, xm, W_l_um1, b_l_um1,
                                                  W_r_um1, hm, N_MOVIES);
  k_agg_mean<unsigned short><<<N_USERS / 4, 256, 0, stream>>>(xm, rp_u, col_u, mu, N_USERS);
  k_lin_mfma<true, false><<<LU, 256, 0, stream>>>(mu, xu, W_l_mu1, b_l_mu1,
                                                  W_r_mu1, hu, N_USERS);

  // layer 2 (no activation, f32 out for decoder)
  k_agg_mean<int><<<N_MOVIES / 4, 256, 0, stream>>>(hu, rp_m, col_m, mm, N_MOVIES);
  k_lin_mfma<false, true><<<LM, 256, 0, stream>>>(mm, hm, W_l_um2, b_l_um2,
                                                  W_r_um2, o_movie, N_MOVIES);
  k_agg_mean<unsigned short><<<N_USERS / 4, 256, 0, stream>>>(hm, rp_u, col_u, mu, N_USERS);
  k_lin_mfma<false, true><<<LU, 256, 0, stream>>>(mu, hu, W_l_mu2, b_l_mu2,
                                                  W_r_mu2, o_user, N_USERS);

  // decoder (f32 tables)
  k_decode<<<(N_LABEL * 16) / 256, 256, 0, stream>>>(
      o_user, o_movie, label_src_user, label_dst_movie, out, N_LABEL);
}